// Round 2
// baseline (2175.838 us; speedup 1.0000x reference)
//
#include <hip/hip_runtime.h>
#include <stdint.h>

typedef unsigned short u16;
typedef unsigned int u32;

#define HN 12
#define DH 64
#define DM 768
#define NS 2048
#define NB 8
#define MF 256
#define BN (NB*NS)
#define BH (NB*HN)

#define NRM 0.35355339059327373f  /* 64^-0.25 */
#define RATIO 0.0625f             /* 256^-0.5 */
#define EPSV 1e-4f

__device__ __forceinline__ float b2f(u32 u){ union{u32 i; float f;} x; x.i=u<<16; return x.f; }
__device__ __forceinline__ u32 f2b(float v){ union{float f; u32 u;} x; x.f=v; return (x.u + 0x7FFFu + ((x.u>>16)&1u))>>16; }
__device__ __forceinline__ u32 fkey(float v){ union{float f; u32 u;} x; x.f=v; return (x.u&0x80000000u)? ~x.u : (x.u|0x80000000u); }
__device__ __forceinline__ float funkey(u32 k){ union{u32 u; float f;} x; x.u=(k&0x80000000u)? (k^0x80000000u) : ~k; return x.f; }
__device__ __forceinline__ void bld8(uint4 r, float s, float* f){
  f[0]=b2f(r.x&0xffffu)*s; f[1]=b2f(r.x>>16)*s;
  f[2]=b2f(r.y&0xffffu)*s; f[3]=b2f(r.y>>16)*s;
  f[4]=b2f(r.z&0xffffu)*s; f[5]=b2f(r.z>>16)*s;
  f[6]=b2f(r.w&0xffffu)*s; f[7]=b2f(r.w>>16)*s;
}
// dtype-flexible raw-input loader: idx is the LOGICAL element index (must be %8==0... %4 for f32 float4)
__device__ __forceinline__ void load8(const void* base, size_t idx, int isf32, float s, float* f){
  if(isf32){
    const float* p=(const float*)base + idx;
    const float4 u=((const float4*)p)[0], v=((const float4*)p)[1];
    f[0]=u.x*s; f[1]=u.y*s; f[2]=u.z*s; f[3]=u.w*s;
    f[4]=v.x*s; f[5]=v.y*s; f[6]=v.z*s; f[7]=v.w*s;
  }else{
    uint4 r=*(const uint4*)((const u16*)base+idx);
    bld8(r,s,f);
  }
}
__device__ __forceinline__ float ld1(const void* base, int idx, int isf32){
  return isf32 ? ((const float*)base)[idx] : b2f((u32)((const u16*)base)[idx]);
}

#define GEMM_K(NK,As,Bs,acc,tr,tc) \
  _Pragma("unroll") \
  for(int kk=0;kk<NK;++kk){ \
    const float4 a4=*(const float4*)&As[kk][tr]; \
    const float4 b4=*(const float4*)&Bs[kk][tc]; \
    const float av_[4]={a4.x,a4.y,a4.z,a4.w}; \
    const float bw_[4]={b4.x,b4.y,b4.z,b4.w}; \
    _Pragma("unroll") for(int ii=0;ii<4;++ii){ \
      _Pragma("unroll") for(int jj=0;jj<4;++jj) acc[ii][jj]+=av_[ii]*bw_[jj]; } \
  }

// ---------------- K0: detect input dtype (0=bf16, 1=f32) ---------------------
__global__ __launch_bounds__(64) void k_detect(const u16* __restrict__ x, int* __restrict__ flag)
{
  __shared__ int w[64], z[64];
  const int t=threadIdx.x;
  int wild=0, zero=0;
  for(int i=t;i<256;i+=64){
    u32 u=(u32)x[2*i];            // low half of f32 elem i, or bf16 elem 2i
    u32 e=(u>>7)&0xFFu;
    if(e>=0x90u) wild++;          // |v|>=2^17 or NaN/Inf: impossible for N(0,1) bf16
    if((u&0x7FFFu)==0u) zero++;   // f32-on-bf16-grid: low halves all zero
  }
  w[t]=wild; z[t]=zero; __syncthreads();
  if(t==0){
    int W=0,Z=0;
    for(int i=0;i<64;++i){W+=w[i];Z+=z[i];}
    flag[0]=(W>16||Z>200)?1:0;
  }
}

// ---------------- K1: fused QKV projection  q/k/v[b,h,n,dh] = x@W*.T + b* ----
__global__ __launch_bounds__(256) void k_qkv(const void* __restrict__ x,
    const void* __restrict__ Wq, const void* __restrict__ Wk, const void* __restrict__ Wv,
    const void* __restrict__ bq, const void* __restrict__ bk, const void* __restrict__ bv,
    u16* __restrict__ qo, u16* __restrict__ ko, u16* __restrict__ vo, const int* __restrict__ flagp)
{
  __shared__ float As[32][68];
  __shared__ float Bs[32][68];
  const int isf32=*flagp;
  const int t=threadIdx.x;
  const int tile_r=blockIdx.x*64;
  const int tcg=blockIdx.y*64;
  const int which=tcg/DM, wc0=tcg%DM;
  const void* W    = which==0?Wq:(which==1?Wk:Wv);
  const void* bias = which==0?bq:(which==1?bk:bv);
  u16* outp        = which==0?qo:(which==1?ko:vo);
  const int a_r=t>>2, a_c=(t&3)*8;
  const int tr=(t>>4)*4, tc=(t&15)*4;
  float acc[4][4]={};
  for(int k0=0;k0<DM;k0+=32){
    float af[8], bf[8];
    load8(x, (size_t)(tile_r+a_r)*DM + k0 + a_c, isf32, 1.0f, af);
    load8(W, (size_t)(wc0+a_r)*DM + k0 + a_c, isf32, 1.0f, bf);
    __syncthreads();
#pragma unroll
    for(int j=0;j<8;++j){ As[a_c+j][a_r]=af[j]; Bs[a_c+j][a_r]=bf[j]; }
    __syncthreads();
    GEMM_K(32,As,Bs,acc,tr,tc)
  }
#pragma unroll
  for(int i=0;i<4;++i){
    const int grow=tile_r+tr+i;
    const int b_=grow>>11, n=grow&2047;
    const int jw=wc0+tc;
    const int h=jw>>6, dd=jw&63;
    uint2 st;
    st.x = f2b(acc[i][0]+ld1(bias,jw,isf32))   | (f2b(acc[i][1]+ld1(bias,jw+1,isf32))<<16);
    st.y = f2b(acc[i][2]+ld1(bias,jw+2,isf32)) | (f2b(acc[i][3]+ld1(bias,jw+3,isf32))<<16);
    *(uint2*)(outp + ((size_t)((b_*HN+h)*NS+n))*DH + dd) = st;
  }
}

// ---------------- K2: xp_k tile + global max per (b,h) -----------------------
__global__ __launch_bounds__(256) void k_xpk_max(const u16* __restrict__ kb,
    const void* __restrict__ proj, u32* __restrict__ kmax, const int* __restrict__ flagp)
{
  __shared__ float As[64][68];
  __shared__ float Bs[64][68];
  __shared__ float red[256];
  const int isf32=*flagp;
  const int t=threadIdx.x;
  const int bh=blockIdx.z, tile_n=blockIdx.x*64, tile_m=blockIdx.y*64;
  const int a_r=t>>2, a_c=(t&3)*16;
  const u16* ap = kb + ((size_t)bh*NS + tile_n + a_r)*DH + a_c;
  uint4 av0=*(const uint4*)ap, av1=*(const uint4*)(ap+8);
  float f0[8],f1[8],g0[8],g1[8];
  bld8(av0,NRM,f0); bld8(av1,NRM,f1);
  load8(proj,(size_t)(tile_m+a_r)*DH+a_c,  isf32,1.0f,g0);
  load8(proj,(size_t)(tile_m+a_r)*DH+a_c+8,isf32,1.0f,g1);
#pragma unroll
  for(int j=0;j<8;++j){
    As[a_c+j][a_r]=f0[j]; As[a_c+8+j][a_r]=f1[j];
    Bs[a_c+j][a_r]=g0[j]; Bs[a_c+8+j][a_r]=g1[j];
  }
  __syncthreads();
  const int tr=(t>>4)*4, tc=(t&15)*4;
  float acc[4][4]={};
  GEMM_K(64,As,Bs,acc,tr,tc)
  float m=acc[0][0];
#pragma unroll
  for(int i=0;i<4;++i)
#pragma unroll
    for(int j=0;j<4;++j) m=fmaxf(m,acc[i][j]);
  red[t]=m; __syncthreads();
  for(int s=128;s>0;s>>=1){ if(t<s) red[t]=fmaxf(red[t],red[t+s]); __syncthreads(); }
  if(t==0) atomicMax(kmax+bh, fkey(red[0]));
}

// ---------------- K3: fused kp -> ksum + ctx (no kp materialization) ---------
// grid (MF/64, BH, 4 n-splits); ctx,ksum accumulated via atomicAdd (pre-zeroed)
__global__ __launch_bounds__(256) void k_ctxsum(const u16* __restrict__ kb,
    const u16* __restrict__ vb, const void* __restrict__ proj,
    const u32* __restrict__ kmax, float* __restrict__ ctx, float* __restrict__ ksum,
    const int* __restrict__ flagp)
{
  __shared__ float As[64][68];   // phase A: k·NRM [d][n]; phase B: v [n][d]
  __shared__ float Bp[64][68];   // proj [d][m] (loaded once)
  __shared__ float Ks[64][68];   // kp [n][m]
  __shared__ float diag_s[64];
  __shared__ float ksum_s[64];
  const int isf32=*flagp;
  const int t=threadIdx.x;
  const int tile_m=blockIdx.x*64, bh=blockIdx.y, split=blockIdx.z;
  const int a_r=t>>2, a_c=(t&3)*16;
  const int tr=(t>>4)*4, tc=(t&15)*4;
  {
    float g0[8],g1[8];
    load8(proj,(size_t)(tile_m+a_r)*DH+a_c,  isf32,1.0f,g0);
    load8(proj,(size_t)(tile_m+a_r)*DH+a_c+8,isf32,1.0f,g1);
#pragma unroll
    for(int j=0;j<8;++j){ Bp[a_c+j][a_r]=g0[j]; Bp[a_c+8+j][a_r]=g1[j]; }
  }
  if(t<64) ksum_s[t]=0.f;
  const float kM=funkey(kmax[bh]);
  float ctx_acc[4][4]={};
  for(int c0=0;c0<512;c0+=64){
    const int n0=split*512+c0;
    const u16* ap = kb + ((size_t)bh*NS + n0 + a_r)*DH + a_c;
    uint4 av0=*(const uint4*)ap, av1=*(const uint4*)(ap+8);
    float f0[8],f1[8];
    bld8(av0,NRM,f0); bld8(av1,NRM,f1);
    __syncthreads();                       // (A) prev GEMM2 readers of As/Ks done; Bp ready
#pragma unroll
    for(int j=0;j<8;++j){ As[a_c+j][a_r]=f0[j]; As[a_c+8+j][a_r]=f1[j]; }  // [d][n]
    __syncthreads();                       // (B)
    float x1[4][4]={};
    GEMM_K(64,As,Bp,x1,tr,tc)
    if(t<64){
      float d=0.f;
#pragma unroll
      for(int kk=0;kk<64;++kk){ float a=As[kk][t]; d+=a*a; }
      diag_s[t]=0.5f*d;
    }
    __syncthreads();                       // (C) diag visible, As reads done
#pragma unroll
    for(int i=0;i<4;++i){
      const float dg=diag_s[tr+i];
#pragma unroll
      for(int j=0;j<4;++j) Ks[tr+i][tc+j]=RATIO*(__expf(x1[i][j]-dg-kM)+EPSV);
    }
    const u16* vp = vb + ((size_t)bh*NS + n0 + a_r)*DH + a_c;
    uint4 bv0=*(const uint4*)vp, bv1=*(const uint4*)(vp+8);
    float g0[8],g1[8];
    bld8(bv0,1.0f,g0); bld8(bv1,1.0f,g1);
    __syncthreads();                       // (D) Ks complete; As free
#pragma unroll
    for(int j=0;j<8;++j){ As[a_r][a_c+j]=g0[j]; As[a_r][a_c+8+j]=g1[j]; }  // v [n][d]
    if(t<64){
      float s=0.f;
#pragma unroll
      for(int n=0;n<64;++n) s+=Ks[n][t];
      ksum_s[t]+=s;
    }
    __syncthreads();                       // (E)
    GEMM_K(64,Ks,As,ctx_acc,tr,tc)         // ctx[m][d] += kp^T @ v
  }
#pragma unroll
  for(int i=0;i<4;++i)
#pragma unroll
    for(int j=0;j<4;++j)
      atomicAdd(ctx + ((size_t)bh*MF + tile_m+tr+i)*DH + tc+j, ctx_acc[i][j]);
  if(t<64) atomicAdd(ksum + bh*MF + tile_m + t, ksum_s[t]);
}

// ---------------- K4: fused qp + D_inv + attn = D_inv*(qp@ctx) ---------------
// grid (NS/32, BH): 32 q-rows per block, full M=256 in LDS, no qp materialization
__global__ __launch_bounds__(256) void k_attn_f(const u16* __restrict__ qb,
    const void* __restrict__ proj, const float* __restrict__ ksum,
    const float* __restrict__ ctx, u16* __restrict__ attn, const int* __restrict__ flagp)
{
  __shared__ float As[64][36];      // q·NRM [d][n], 32 rows
  __shared__ u16   Bbuf[64*256];    // phase1: proj [d][m] bf16 ; phase2: qp [m][36] bf16
  __shared__ float Cs[64*68];       // phase1: misc overlay ; phase2: ctx chunk [64][68]
  __shared__ float dinv_s[32];
  float* red   = Cs;                // [32][33]
  float* rstat = Cs+1056;
  float* dstat = Cs+1088;
  float* ks    = Cs+1120;           // [256]
  const int isf32=*flagp;
  const int t=threadIdx.x;
  const int bh=blockIdx.y, n0=blockIdx.x*32;
  {
    const int r=t>>3, c=(t&7)*8;
    uint4 a=*(const uint4*)(qb + ((size_t)bh*NS + n0 + r)*DH + c);
    float af[8]; bld8(a,NRM,af);
#pragma unroll
    for(int j=0;j<8;++j) As[c+j][r]=af[j];
  }
  {
    float pf[8];
#pragma unroll
    for(int c=0;c<64;c+=8){
      load8(proj,(size_t)t*DH+c,isf32,1.0f,pf);
#pragma unroll
      for(int j=0;j<8;++j) Bbuf[(c+j)*256+t]=(u16)f2b(pf[j]);
    }
  }
  ks[t]=ksum[bh*MF+t];
  __syncthreads();                                  // S1
  const int rg=(t>>5)*4, cg=(t&31)*4;
  float acc[4][8]={};
#pragma unroll
  for(int kk=0;kk<64;++kk){
    const float4 a4=*(const float4*)&As[kk][rg];
    const u16* prow=Bbuf+kk*256;
    const ushort4 b0=*(const ushort4*)(prow+cg);
    const ushort4 b1=*(const ushort4*)(prow+cg+128);
    const float av_[4]={a4.x,a4.y,a4.z,a4.w};
    const float bf0[4]={b2f((u32)b0.x),b2f((u32)b0.y),b2f((u32)b0.z),b2f((u32)b0.w)};
    const float bf1[4]={b2f((u32)b1.x),b2f((u32)b1.y),b2f((u32)b1.z),b2f((u32)b1.w)};
#pragma unroll
    for(int i=0;i<4;++i){
#pragma unroll
      for(int j=0;j<4;++j){ acc[i][j]+=av_[i]*bf0[j]; acc[i][4+j]+=av_[i]*bf1[j]; }
    }
  }
#pragma unroll
  for(int i=0;i<4;++i){
    float m=acc[i][0];
#pragma unroll
    for(int j=1;j<8;++j) m=fmaxf(m,acc[i][j]);
    red[(rg+i)*33+(t&31)]=m;
  }
  __syncthreads();                                  // S2
  if(t<32){
    float m=red[t*33];
#pragma unroll
    for(int j=1;j<32;++j) m=fmaxf(m,red[t*33+j]);
    rstat[t]=m;
    float d=0.f;
#pragma unroll
    for(int kk=0;kk<64;++kk){ float a=As[kk][t]; d+=a*a; }
    dstat[t]=0.5f*d;
  }
  __syncthreads();                                  // S3
  float qf[4][8], pd[4];
#pragma unroll
  for(int i=0;i<4;++i){
    const int r=rg+i;
    const float mm=rstat[r]+dstat[r];
    float p=0.f;
#pragma unroll
    for(int j=0;j<4;++j){ qf[i][j]  =RATIO*(__expf(acc[i][j]  -mm)+EPSV); p+=qf[i][j]  *ks[cg+j]; }
#pragma unroll
    for(int j=0;j<4;++j){ qf[i][4+j]=RATIO*(__expf(acc[i][4+j]-mm)+EPSV); p+=qf[i][4+j]*ks[128+cg+j]; }
    pd[i]=p;
  }
  __syncthreads();                                  // S4: proj/ks/rstat reads done
#pragma unroll
  for(int i=0;i<4;++i){
#pragma unroll
    for(int j=0;j<4;++j){
      Bbuf[(cg+j)*36     + rg+i]=(u16)f2b(qf[i][j]);
      Bbuf[(128+cg+j)*36 + rg+i]=(u16)f2b(qf[i][4+j]);
    }
    red[(rg+i)*33+(t&31)]=pd[i];
  }
  __syncthreads();                                  // S5
  if(t<32){
    float s=red[t*33];
#pragma unroll
    for(int j=1;j<32;++j) s+=red[t*33+j];
    dinv_s[t]=1.0f/s;
  }
  // phase 2: attn(32x64) = qp(32x256) @ ctx(256x64), chunks of 64 m
  const int tr2=(t>>5)*4, tc2=(t&31)*2;
  float acc2[4][2]={};
  for(int m0=0;m0<256;m0+=64){
    const float* cp = ctx + ((size_t)bh*MF + m0 + (t>>2))*DH + (t&3)*16;
    float4 c0=((const float4*)cp)[0], c1=((const float4*)cp)[1],
           c2=((const float4*)cp)[2], c3=((const float4*)cp)[3];
    __syncthreads();                                // top: prev readers (incl. dinv red) done
    float* crow=Cs+(size_t)(t>>2)*68+(t&3)*16;
    ((float4*)crow)[0]=c0; ((float4*)crow)[1]=c1; ((float4*)crow)[2]=c2; ((float4*)crow)[3]=c3;
    __syncthreads();
#pragma unroll
    for(int mm=0;mm<64;++mm){
      const ushort4 a4=*(const ushort4*)(Bbuf+(m0+mm)*36+tr2);
      const float b0=Cs[mm*68+tc2], b1=Cs[mm*68+tc2+1];
      const float av_[4]={b2f((u32)a4.x),b2f((u32)a4.y),b2f((u32)a4.z),b2f((u32)a4.w)};
#pragma unroll
      for(int i=0;i<4;++i){ acc2[i][0]+=av_[i]*b0; acc2[i][1]+=av_[i]*b1; }
    }
  }
  const int b_=bh/HN, h=bh%HN;
#pragma unroll
  for(int i=0;i<4;++i){
    const int n=n0+tr2+i;
    const float sc=dinv_s[tr2+i];
    u32 st=f2b(acc2[i][0]*sc)|(f2b(acc2[i][1]*sc)<<16);
    *(u32*)(attn + ((size_t)(b_*NS+n))*DM + h*DH + tc2) = st;
  }
}

// ---------------- K5: final out = attn @ Wo.T + bo ---------------------------
__global__ __launch_bounds__(256) void k_out(const u16* __restrict__ attn,
    const void* __restrict__ Wo, const void* __restrict__ bo, void* __restrict__ outv,
    const int* __restrict__ flagp)
{
  __shared__ float As[32][68];
  __shared__ float Bs[32][68];
  const int isf32=*flagp;
  const int t=threadIdx.x;
  const int tile_r=blockIdx.x*64, wc0=blockIdx.y*64;
  const int a_r=t>>2, a_c=(t&3)*8;
  const int tr=(t>>4)*4, tc=(t&15)*4;
  float acc[4][4]={};
  for(int k0=0;k0<DM;k0+=32){
    uint4 avv=*(const uint4*)(attn + (size_t)(tile_r+a_r)*DM + k0 + a_c);
    float af[8], bf[8];
    bld8(avv,1.0f,af);
    load8(Wo, (size_t)(wc0+a_r)*DM + k0 + a_c, isf32, 1.0f, bf);
    __syncthreads();
#pragma unroll
    for(int j=0;j<8;++j){ As[a_c+j][a_r]=af[j]; Bs[a_c+j][a_r]=bf[j]; }
    __syncthreads();
    GEMM_K(32,As,Bs,acc,tr,tc)
  }
#pragma unroll
  for(int i=0;i<4;++i){
    const int grow=tile_r+tr+i;
    const int jw=wc0+tc;
    float v0=acc[i][0]+ld1(bo,jw,isf32),   v1=acc[i][1]+ld1(bo,jw+1,isf32);
    float v2=acc[i][2]+ld1(bo,jw+2,isf32), v3=acc[i][3]+ld1(bo,jw+3,isf32);
    if(isf32){
      float4 st; st.x=v0; st.y=v1; st.z=v2; st.w=v3;
      *(float4*)((float*)outv + (size_t)grow*DM + jw)=st;
    }else{
      uint2 st;
      st.x=f2b(v0)|(f2b(v1)<<16); st.y=f2b(v2)|(f2b(v3)<<16);
      *(uint2*)((u16*)outv + (size_t)grow*DM + jw)=st;
    }
  }
}

extern "C" void kernel_launch(void* const* d_in, const int* in_sizes, int n_in,
                              void* d_out, int out_size, void* d_ws, size_t ws_size,
                              hipStream_t stream)
{
  (void)in_sizes; (void)n_in; (void)out_size; (void)ws_size;
  const void* x =d_in[0];
  const void* Wq=d_in[1]; const void* bq=d_in[2];
  const void* Wk=d_in[3]; const void* bk=d_in[4];
  const void* Wv=d_in[5]; const void* bv=d_in[6];
  const void* Wo=d_in[7]; const void* bo=d_in[8];
  const void* proj=d_in[9];

  char* ws=(char*)d_ws;
  const size_t SZ=(size_t)BN*DM*2;               // 25,165,824 B
  u16*   qb   =(u16*)(ws);
  u16*   kb   =(u16*)(ws+SZ);
  u16*   vb   =(u16*)(ws+2*SZ);
  u16*   attnb=(u16*)(ws+3*SZ);
  float* ctx  =(float*)(ws+4*SZ);                // BH*MF*DH*4 = 6,291,456 B
  float* ksum =(float*)(ws+4*SZ+6291456);        // 98,304 B
  u32*   kmax =(u32*)(ws+4*SZ+6389760);          // 384 B
  int*   flag =(int*)(ws+4*SZ+6390144);          // 16 B
  // total ~102.1 MB

  k_detect<<<1,64,0,stream>>>((const u16*)x, flag);
  hipMemsetAsync(ctx, 0, 6291456+98304+384, stream);   // ctx + ksum + kmax
  k_qkv    <<<dim3(BN/64,(3*DM)/64), 256, 0, stream>>>(x,Wq,Wk,Wv,bq,bk,bv,qb,kb,vb,flag);
  k_xpk_max<<<dim3(NS/64,MF/64,BH),  256, 0, stream>>>(kb,proj,kmax,flag);
  k_ctxsum <<<dim3(MF/64,BH,4),      256, 0, stream>>>(kb,vb,proj,kmax,ctx,ksum,flag);
  k_attn_f <<<dim3(NS/32,BH),        256, 0, stream>>>(qb,proj,ksum,ctx,attnb,flag);
  k_out    <<<dim3(BN/64,DM/64),     256, 0, stream>>>(attnb,Wo,bo,d_out,flag);
}

// Round 3
// 1317.310 us; speedup vs baseline: 1.6517x; 1.6517x over previous
//
#include <hip/hip_runtime.h>
#include <stdint.h>

typedef unsigned short u16;
typedef unsigned int u32;
typedef __attribute__((ext_vector_type(8))) short short8;
typedef __attribute__((ext_vector_type(4))) float floatx4;

#define HN 12
#define DH 64
#define DM 768
#define NS 2048
#define NB 8
#define MF 256
#define BN (NB*NS)
#define BH (NB*HN)

#define NRM 0.35355339059327373f  /* 64^-0.25 */
#define RATIO 0.0625f             /* 256^-0.5 */
#define EPSV 1e-4f

__device__ __forceinline__ float b2f(u32 u){ union{u32 i; float f;} x; x.i=u<<16; return x.f; }
__device__ __forceinline__ u32 f2b(float v){ union{float f; u32 u;} x; x.f=v; return (x.u + 0x7FFFu + ((x.u>>16)&1u))>>16; }
__device__ __forceinline__ u32 fkey(float v){ union{float f; u32 u;} x; x.f=v; return (x.u&0x80000000u)? ~x.u : (x.u|0x80000000u); }
__device__ __forceinline__ float funkey(u32 k){ union{u32 u; float f;} x; x.u=(k&0x80000000u)? (k^0x80000000u) : ~k; return x.f; }
__device__ __forceinline__ void bld8(uint4 r, float s, float* f){
  f[0]=b2f(r.x&0xffffu)*s; f[1]=b2f(r.x>>16)*s;
  f[2]=b2f(r.y&0xffffu)*s; f[3]=b2f(r.y>>16)*s;
  f[4]=b2f(r.z&0xffffu)*s; f[5]=b2f(r.z>>16)*s;
  f[6]=b2f(r.w&0xffffu)*s; f[7]=b2f(r.w>>16)*s;
}
__device__ __forceinline__ void load8(const void* base, size_t idx, int isf32, float s, float* f){
  if(isf32){
    const float* p=(const float*)base + idx;
    const float4 u=((const float4*)p)[0], v=((const float4*)p)[1];
    f[0]=u.x*s; f[1]=u.y*s; f[2]=u.z*s; f[3]=u.w*s;
    f[4]=v.x*s; f[5]=v.y*s; f[6]=v.z*s; f[7]=v.w*s;
  }else{
    uint4 r=*(const uint4*)((const u16*)base+idx);
    bld8(r,s,f);
  }
}
__device__ __forceinline__ float ld1(const void* base, int idx, int isf32){
  return isf32 ? ((const float*)base)[idx] : b2f((u32)((const u16*)base)[idx]);
}

#define GEMM_K(NK,As,Bs,acc,tr,tc) \
  _Pragma("unroll") \
  for(int kk=0;kk<NK;++kk){ \
    const float4 a4=*(const float4*)&As[kk][tr]; \
    const float4 b4=*(const float4*)&Bs[kk][tc]; \
    const float av_[4]={a4.x,a4.y,a4.z,a4.w}; \
    const float bw_[4]={b4.x,b4.y,b4.z,b4.w}; \
    _Pragma("unroll") for(int ii=0;ii<4;++ii){ \
      _Pragma("unroll") for(int jj=0;jj<4;++jj) acc[ii][jj]+=av_[ii]*bw_[jj]; } \
  }

// ---------------- K0: detect input dtype (0=bf16, 1=f32) ---------------------
__global__ __launch_bounds__(64) void k_detect(const u16* __restrict__ x, int* __restrict__ flag)
{
  __shared__ int w[64], z[64];
  const int t=threadIdx.x;
  int wild=0, zero=0;
  for(int i=t;i<256;i+=64){
    u32 u=(u32)x[2*i];
    u32 e=(u>>7)&0xFFu;
    if(e>=0x90u) wild++;
    if((u&0x7FFFu)==0u) zero++;
  }
  w[t]=wild; z[t]=zero; __syncthreads();
  if(t==0){
    int W=0,Z=0;
    for(int i=0;i<64;++i){W+=w[i];Z+=z[i];}
    flag[0]=(W>16||Z>200)?1:0;
  }
}

// ---------------- K0b: convert weights to bf16 (wb=[Wq;Wk;Wv], wob=Wo) ------
__global__ __launch_bounds__(256) void k_cvtw(const void* __restrict__ Wq,
    const void* __restrict__ Wk, const void* __restrict__ Wv, const void* __restrict__ Wo,
    u16* __restrict__ wb, u16* __restrict__ wob, const int* __restrict__ flagp)
{
  const int isf32=*flagp;
  const size_t WSZ=(size_t)DM*DM;                       // 589824
  size_t idx=((size_t)blockIdx.x*256+threadIdx.x)*8;    // flat over 4*WSZ
  const void* src; size_t off; u16* dst;
  if(idx<3*WSZ){ int w=(int)(idx/WSZ); src=(w==0)?Wq:((w==1)?Wk:Wv); off=idx-(size_t)w*WSZ; dst=wb+idx; }
  else { src=Wo; off=idx-3*WSZ; dst=wob+off; }
  if(isf32){
    const float* p=(const float*)src+off;
    float4 u=((const float4*)p)[0], v=((const float4*)p)[1];
    uint4 st;
    st.x=f2b(u.x)|(f2b(u.y)<<16); st.y=f2b(u.z)|(f2b(u.w)<<16);
    st.z=f2b(v.x)|(f2b(v.y)<<16); st.w=f2b(v.z)|(f2b(v.w)<<16);
    *(uint4*)dst=st;
  }else{
    *(uint4*)dst=*(const uint4*)((const u16*)src+off);
  }
}

// ---------------- K1: MFMA GEMM  C[16384 x N] = A[16384x768] @ B[Nx768]^T ----
// mode 0: N=2304, epilogue -> q/k/v (head-interleaved bf16, +bias per third)
// mode 1: N=768,  epilogue -> d_out (+bo, dtype per flag)
__global__ __launch_bounds__(256) void k_gemm(const void* __restrict__ Araw,
    const u16* __restrict__ B16,
    const void* __restrict__ bias0, const void* __restrict__ bias1, const void* __restrict__ bias2,
    u16* __restrict__ q, u16* __restrict__ k, u16* __restrict__ v,
    void* __restrict__ outv, const int* __restrict__ flagp, const int mode)
{
  __shared__ short At[16*512];   // 16 KB: 16 blocks of (16 rows x 32 k), fragment order
  __shared__ short Bt[16*512];
  const int oflag=*flagp;
  const int isf32=(mode==0)?oflag:0;   // A operand dtype (mode1 A is bf16 attn)
  const int t=threadIdx.x, l=t&63, w=t>>6;
  const int m0=blockIdx.x*128, n0=blockIdx.y*128;
  const int wr4=(w>>1)*4, wc4=(w&1)*4;
  const int srow=l&15, skg=l>>4;
  floatx4 acc[4][4]={};
  for(int k0=0;k0<DM;k0+=64){
    __syncthreads();
#pragma unroll
    for(int s=0;s<4;++s){
      const int bi=w*4+s, rb=bi>>1, kh=bi&1;
      const int kc=k0+kh*32+skg*8;
      uint4 va;
      if(isf32){
        const float* ap=(const float*)Araw + (size_t)(m0+rb*16+srow)*DM + kc;
        float4 u=((const float4*)ap)[0], vv=((const float4*)ap)[1];
        va.x=f2b(u.x)|(f2b(u.y)<<16);  va.y=f2b(u.z)|(f2b(u.w)<<16);
        va.z=f2b(vv.x)|(f2b(vv.y)<<16); va.w=f2b(vv.z)|(f2b(vv.w)<<16);
      }else{
        va=*(const uint4*)((const u16*)Araw + (size_t)(m0+rb*16+srow)*DM + kc);
      }
      const uint4 vb=*(const uint4*)(B16 + (size_t)(n0+rb*16+srow)*DM + kc);
      *(uint4*)&At[bi*512+l*8]=va;
      *(uint4*)&Bt[bi*512+l*8]=vb;
    }
    __syncthreads();
#pragma unroll
    for(int kh=0;kh<2;++kh){
      short8 af[4], bf[4];
#pragma unroll
      for(int i=0;i<4;++i) af[i]=*(short8*)&At[((wr4+i)*2+kh)*512+l*8];
#pragma unroll
      for(int j=0;j<4;++j) bf[j]=*(short8*)&Bt[((wc4+j)*2+kh)*512+l*8];
#pragma unroll
      for(int i=0;i<4;++i)
#pragma unroll
        for(int j=0;j<4;++j)
          acc[i][j]=__builtin_amdgcn_mfma_f32_16x16x32_bf16(af[i],bf[j],acc[i][j],0,0,0);
    }
  }
  // epilogue: C/D layout col=lane&15, row=(lane>>4)*4+reg
  const int rbase=(l>>4)*4, cl=l&15;
  if(mode==0){
    const int which=n0/DM;
    const void* bias=(which==0)?bias0:((which==1)?bias1:bias2);
    u16* outp=(which==0)?q:((which==1)?k:v);
    const int cb=n0-which*DM;
#pragma unroll
    for(int j=0;j<4;++j){
      const int col=cb+(wc4+j)*16+cl;
      const int h=col>>6, dd=col&63;
      const float bb=ld1(bias,col,oflag);
#pragma unroll
      for(int i=0;i<4;++i){
#pragma unroll
        for(int r=0;r<4;++r){
          const int grow=m0+(wr4+i)*16+rbase+r;
          const int b_=grow>>11, n=grow&2047;
          outp[((size_t)((b_*HN+h)*NS+n))*DH+dd]=(u16)f2b(acc[i][j][r]+bb);
        }
      }
    }
  }else{
#pragma unroll
    for(int j=0;j<4;++j){
      const int col=n0+(wc4+j)*16+cl;
      const float bb=ld1(bias0,col,oflag);
#pragma unroll
      for(int i=0;i<4;++i){
#pragma unroll
        for(int r=0;r<4;++r){
          const int grow=m0+(wr4+i)*16+rbase+r;
          const float val=acc[i][j][r]+bb;
          if(oflag) ((float*)outv)[(size_t)grow*DM+col]=val;
          else      ((u16*)outv)[(size_t)grow*DM+col]=(u16)f2b(val);
        }
      }
    }
  }
}

// ---------------- K2: xp_k tile + global max per (b,h) -----------------------
__global__ __launch_bounds__(256) void k_xpk_max(const u16* __restrict__ kb,
    const void* __restrict__ proj, u32* __restrict__ kmax, const int* __restrict__ flagp)
{
  __shared__ float As[64][68];
  __shared__ float Bs[64][68];
  __shared__ float red[256];
  const int isf32=*flagp;
  const int t=threadIdx.x;
  const int bh=blockIdx.z, tile_n=blockIdx.x*64, tile_m=blockIdx.y*64;
  const int a_r=t>>2, a_c=(t&3)*16;
  const u16* ap = kb + ((size_t)bh*NS + tile_n + a_r)*DH + a_c;
  uint4 av0=*(const uint4*)ap, av1=*(const uint4*)(ap+8);
  float f0[8],f1[8],g0[8],g1[8];
  bld8(av0,NRM,f0); bld8(av1,NRM,f1);
  load8(proj,(size_t)(tile_m+a_r)*DH+a_c,  isf32,1.0f,g0);
  load8(proj,(size_t)(tile_m+a_r)*DH+a_c+8,isf32,1.0f,g1);
#pragma unroll
  for(int j=0;j<8;++j){
    As[a_c+j][a_r]=f0[j]; As[a_c+8+j][a_r]=f1[j];
    Bs[a_c+j][a_r]=g0[j]; Bs[a_c+8+j][a_r]=g1[j];
  }
  __syncthreads();
  const int tr=(t>>4)*4, tc=(t&15)*4;
  float acc[4][4]={};
  GEMM_K(64,As,Bs,acc,tr,tc)
  float m=acc[0][0];
#pragma unroll
  for(int i=0;i<4;++i)
#pragma unroll
    for(int j=0;j<4;++j) m=fmaxf(m,acc[i][j]);
  red[t]=m; __syncthreads();
  for(int s=128;s>0;s>>=1){ if(t<s) red[t]=fmaxf(red[t],red[t+s]); __syncthreads(); }
  if(t==0) atomicMax(kmax+bh, fkey(red[0]));
}

// ---------------- K3: fused kp -> ksum + ctx (no kp materialization) ---------
__global__ __launch_bounds__(256) void k_ctxsum(const u16* __restrict__ kb,
    const u16* __restrict__ vb, const void* __restrict__ proj,
    const u32* __restrict__ kmax, float* __restrict__ ctx, float* __restrict__ ksum,
    const int* __restrict__ flagp)
{
  __shared__ float As[64][68];
  __shared__ float Bp[64][68];
  __shared__ float Ks[64][68];
  __shared__ float diag_s[64];
  __shared__ float ksum_s[64];
  const int isf32=*flagp;
  const int t=threadIdx.x;
  const int tile_m=blockIdx.x*64, bh=blockIdx.y, split=blockIdx.z;
  const int a_r=t>>2, a_c=(t&3)*16;
  const int tr=(t>>4)*4, tc=(t&15)*4;
  {
    float g0[8],g1[8];
    load8(proj,(size_t)(tile_m+a_r)*DH+a_c,  isf32,1.0f,g0);
    load8(proj,(size_t)(tile_m+a_r)*DH+a_c+8,isf32,1.0f,g1);
#pragma unroll
    for(int j=0;j<8;++j){ Bp[a_c+j][a_r]=g0[j]; Bp[a_c+8+j][a_r]=g1[j]; }
  }
  if(t<64) ksum_s[t]=0.f;
  const float kM=funkey(kmax[bh]);
  float ctx_acc[4][4]={};
  for(int c0=0;c0<512;c0+=64){
    const int n0=split*512+c0;
    const u16* ap = kb + ((size_t)bh*NS + n0 + a_r)*DH + a_c;
    uint4 av0=*(const uint4*)ap, av1=*(const uint4*)(ap+8);
    float f0[8],f1[8];
    bld8(av0,NRM,f0); bld8(av1,NRM,f1);
    __syncthreads();
#pragma unroll
    for(int j=0;j<8;++j){ As[a_c+j][a_r]=f0[j]; As[a_c+8+j][a_r]=f1[j]; }
    __syncthreads();
    float x1[4][4]={};
    GEMM_K(64,As,Bp,x1,tr,tc)
    if(t<64){
      float d=0.f;
#pragma unroll
      for(int kk=0;kk<64;++kk){ float a=As[kk][t]; d+=a*a; }
      diag_s[t]=0.5f*d;
    }
    __syncthreads();
#pragma unroll
    for(int i=0;i<4;++i){
      const float dg=diag_s[tr+i];
#pragma unroll
      for(int j=0;j<4;++j) Ks[tr+i][tc+j]=RATIO*(__expf(x1[i][j]-dg-kM)+EPSV);
    }
    const u16* vp = vb + ((size_t)bh*NS + n0 + a_r)*DH + a_c;
    uint4 bv0=*(const uint4*)vp, bv1=*(const uint4*)(vp+8);
    float g0[8],g1[8];
    bld8(bv0,1.0f,g0); bld8(bv1,1.0f,g1);
    __syncthreads();
#pragma unroll
    for(int j=0;j<8;++j){ As[a_r][a_c+j]=g0[j]; As[a_r][a_c+8+j]=g1[j]; }
    if(t<64){
      float s=0.f;
#pragma unroll
      for(int n=0;n<64;++n) s+=Ks[n][t];
      ksum_s[t]+=s;
    }
    __syncthreads();
    GEMM_K(64,Ks,As,ctx_acc,tr,tc)
  }
#pragma unroll
  for(int i=0;i<4;++i)
#pragma unroll
    for(int j=0;j<4;++j)
      atomicAdd(ctx + ((size_t)bh*MF + tile_m+tr+i)*DH + tc+j, ctx_acc[i][j]);
  if(t<64) atomicAdd(ksum + bh*MF + tile_m + t, ksum_s[t]);
}

// ---------------- K4: fused qp + D_inv + attn = D_inv*(qp@ctx) ---------------
__global__ __launch_bounds__(256) void k_attn_f(const u16* __restrict__ qb,
    const void* __restrict__ proj, const float* __restrict__ ksum,
    const float* __restrict__ ctx, u16* __restrict__ attn, const int* __restrict__ flagp)
{
  __shared__ float As[64][36];
  __shared__ u16   Bbuf[64*256];
  __shared__ float Cs[64*68];
  __shared__ float dinv_s[32];
  float* red   = Cs;
  float* rstat = Cs+1056;
  float* dstat = Cs+1088;
  float* ks    = Cs+1120;
  const int isf32=*flagp;
  const int t=threadIdx.x;
  const int bh=blockIdx.y, n0=blockIdx.x*32;
  {
    const int r=t>>3, c=(t&7)*8;
    uint4 a=*(const uint4*)(qb + ((size_t)bh*NS + n0 + r)*DH + c);
    float af[8]; bld8(a,NRM,af);
#pragma unroll
    for(int j=0;j<8;++j) As[c+j][r]=af[j];
  }
  {
    float pf[8];
#pragma unroll
    for(int c=0;c<64;c+=8){
      load8(proj,(size_t)t*DH+c,isf32,1.0f,pf);
#pragma unroll
      for(int j=0;j<8;++j) Bbuf[(c+j)*256+t]=(u16)f2b(pf[j]);
    }
  }
  ks[t]=ksum[bh*MF+t];
  __syncthreads();
  const int rg=(t>>5)*4, cg=(t&31)*4;
  float acc[4][8]={};
#pragma unroll
  for(int kk=0;kk<64;++kk){
    const float4 a4=*(const float4*)&As[kk][rg];
    const u16* prow=Bbuf+kk*256;
    const ushort4 b0=*(const ushort4*)(prow+cg);
    const ushort4 b1=*(const ushort4*)(prow+cg+128);
    const float av_[4]={a4.x,a4.y,a4.z,a4.w};
    const float bf0[4]={b2f((u32)b0.x),b2f((u32)b0.y),b2f((u32)b0.z),b2f((u32)b0.w)};
    const float bf1[4]={b2f((u32)b1.x),b2f((u32)b1.y),b2f((u32)b1.z),b2f((u32)b1.w)};
#pragma unroll
    for(int i=0;i<4;++i){
#pragma unroll
      for(int j=0;j<4;++j){ acc[i][j]+=av_[i]*bf0[j]; acc[i][4+j]+=av_[i]*bf1[j]; }
    }
  }
#pragma unroll
  for(int i=0;i<4;++i){
    float m=acc[i][0];
#pragma unroll
    for(int j=1;j<8;++j) m=fmaxf(m,acc[i][j]);
    red[(rg+i)*33+(t&31)]=m;
  }
  __syncthreads();
  if(t<32){
    float m=red[t*33];
#pragma unroll
    for(int j=1;j<32;++j) m=fmaxf(m,red[t*33+j]);
    rstat[t]=m;
    float d=0.f;
#pragma unroll
    for(int kk=0;kk<64;++kk){ float a=As[kk][t]; d+=a*a; }
    dstat[t]=0.5f*d;
  }
  __syncthreads();
  float qf[4][8], pd[4];
#pragma unroll
  for(int i=0;i<4;++i){
    const int r=rg+i;
    const float mm=rstat[r]+dstat[r];
    float p=0.f;
#pragma unroll
    for(int j=0;j<4;++j){ qf[i][j]  =RATIO*(__expf(acc[i][j]  -mm)+EPSV); p+=qf[i][j]  *ks[cg+j]; }
#pragma unroll
    for(int j=0;j<4;++j){ qf[i][4+j]=RATIO*(__expf(acc[i][4+j]-mm)+EPSV); p+=qf[i][4+j]*ks[128+cg+j]; }
    pd[i]=p;
  }
  __syncthreads();
#pragma unroll
  for(int i=0;i<4;++i){
#pragma unroll
    for(int j=0;j<4;++j){
      Bbuf[(cg+j)*36     + rg+i]=(u16)f2b(qf[i][j]);
      Bbuf[(128+cg+j)*36 + rg+i]=(u16)f2b(qf[i][4+j]);
    }
    red[(rg+i)*33+(t&31)]=pd[i];
  }
  __syncthreads();
  if(t<32){
    float s=red[t*33];
#pragma unroll
    for(int j=1;j<32;++j) s+=red[t*33+j];
    dinv_s[t]=1.0f/s;
  }
  const int tr2=(t>>5)*4, tc2=(t&31)*2;
  float acc2[4][2]={};
  for(int m0=0;m0<256;m0+=64){
    const float* cp = ctx + ((size_t)bh*MF + m0 + (t>>2))*DH + (t&3)*16;
    float4 c0=((const float4*)cp)[0], c1=((const float4*)cp)[1],
           c2=((const float4*)cp)[2], c3=((const float4*)cp)[3];
    __syncthreads();
    float* crow=Cs+(size_t)(t>>2)*68+(t&3)*16;
    ((float4*)crow)[0]=c0; ((float4*)crow)[1]=c1; ((float4*)crow)[2]=c2; ((float4*)crow)[3]=c3;
    __syncthreads();
#pragma unroll
    for(int mm=0;mm<64;++mm){
      const ushort4 a4=*(const ushort4*)(Bbuf+(m0+mm)*36+tr2);
      const float b0=Cs[mm*68+tc2], b1=Cs[mm*68+tc2+1];
      const float av_[4]={b2f((u32)a4.x),b2f((u32)a4.y),b2f((u32)a4.z),b2f((u32)a4.w)};
#pragma unroll
      for(int i=0;i<4;++i){ acc2[i][0]+=av_[i]*b0; acc2[i][1]+=av_[i]*b1; }
    }
  }
  const int b_=bh/HN, h=bh%HN;
#pragma unroll
  for(int i=0;i<4;++i){
    const int n=n0+tr2+i;
    const float sc=dinv_s[tr2+i];
    u32 st=f2b(acc2[i][0]*sc)|(f2b(acc2[i][1]*sc)<<16);
    *(u32*)(attn + ((size_t)(b_*NS+n))*DM + h*DH + tc2) = st;
  }
}

extern "C" void kernel_launch(void* const* d_in, const int* in_sizes, int n_in,
                              void* d_out, int out_size, void* d_ws, size_t ws_size,
                              hipStream_t stream)
{
  (void)in_sizes; (void)n_in; (void)out_size; (void)ws_size;
  const void* x =d_in[0];
  const void* Wq=d_in[1]; const void* bq=d_in[2];
  const void* Wk=d_in[3]; const void* bk=d_in[4];
  const void* Wv=d_in[5]; const void* bv=d_in[6];
  const void* Wo=d_in[7]; const void* bo=d_in[8];
  const void* proj=d_in[9];

  char* ws=(char*)d_ws;
  const size_t SZ=(size_t)BN*DM*2;               // 25,165,824 B
  u16*   qb  =(u16*)(ws);
  u16*   kb  =(u16*)(ws+SZ);
  u16*   vb  =(u16*)(ws+2*SZ);
  u16*   wb  =(u16*)(ws+3*SZ);                   // [2304x768] bf16: 3,538,944 B
  u16*   wob =(u16*)(ws+3*SZ+3538944);           // [768x768]  bf16: 1,179,648 B
  float* ctx =(float*)(ws+3*SZ+4718592);         // 6,291,456 B
  float* ksum=(float*)(ws+3*SZ+11010048);        // 98,304 B
  u32*   kmax=(u32*)(ws+3*SZ+11108352);          // 384 B
  int*   flag=(int*)(ws+3*SZ+11108736);          // 16 B
  u16*   attnb=kb;   // kb dead after k_ctxsum; k_attn_f output reuses it
  // total ~86.6 MB

  k_detect<<<1,64,0,stream>>>((const u16*)x, flag);
  hipMemsetAsync(ctx, 0, 6291456+98304+384, stream);
  k_cvtw   <<<1152, 256, 0, stream>>>(Wq,Wk,Wv,Wo,wb,wob,flag);
  k_gemm   <<<dim3(BN/128,2304/128), 256, 0, stream>>>(x, wb, bq,bk,bv, qb,kb,vb, nullptr, flag, 0);
  k_xpk_max<<<dim3(NS/64,MF/64,BH),  256, 0, stream>>>(kb,proj,kmax,flag);
  k_ctxsum <<<dim3(MF/64,BH,4),      256, 0, stream>>>(kb,vb,proj,kmax,ctx,ksum,flag);
  k_attn_f <<<dim3(NS/32,BH),        256, 0, stream>>>(qb,proj,ksum,ctx,attnb,flag);
  k_gemm   <<<dim3(BN/128,DM/128),   256, 0, stream>>>(attnb, wob, bo,bo,bo, nullptr,nullptr,nullptr, d_out, flag, 1);
}

// Round 4
// 777.646 us; speedup vs baseline: 2.7980x; 1.6940x over previous
//
#include <hip/hip_runtime.h>
#include <stdint.h>

typedef unsigned short u16;
typedef unsigned int u32;
typedef __attribute__((ext_vector_type(8))) short short8;
typedef __attribute__((ext_vector_type(4))) float floatx4;

#define HN 12
#define DH 64
#define DM 768
#define NS 2048
#define NB 8
#define MF 256
#define BN (NB*NS)
#define BH (NB*HN)

#define NRM 0.35355339059327373f  /* 64^-0.25 */
#define RATIO 0.0625f             /* 256^-0.5 */
#define EPSV 1e-4f

__device__ __forceinline__ float b2f(u32 u){ union{u32 i; float f;} x; x.i=u<<16; return x.f; }
__device__ __forceinline__ u32 f2b(float v){ union{float f; u32 u;} x; x.f=v; return (x.u + 0x7FFFu + ((x.u>>16)&1u))>>16; }
__device__ __forceinline__ u32 fkey(float v){ union{float f; u32 u;} x; x.f=v; return (x.u&0x80000000u)? ~x.u : (x.u|0x80000000u); }
__device__ __forceinline__ float funkey(u32 k){ union{u32 u; float f;} x; x.u=(k&0x80000000u)? (k^0x80000000u) : ~k; return x.f; }
__device__ __forceinline__ void bld8(uint4 r, float s, float* f){
  f[0]=b2f(r.x&0xffffu)*s; f[1]=b2f(r.x>>16)*s;
  f[2]=b2f(r.y&0xffffu)*s; f[3]=b2f(r.y>>16)*s;
  f[4]=b2f(r.z&0xffffu)*s; f[5]=b2f(r.z>>16)*s;
  f[6]=b2f(r.w&0xffffu)*s; f[7]=b2f(r.w>>16)*s;
}
__device__ __forceinline__ void load8(const void* base, size_t idx, int isf32, float s, float* f){
  if(isf32){
    const float* p=(const float*)base + idx;
    const float4 u=((const float4*)p)[0], v=((const float4*)p)[1];
    f[0]=u.x*s; f[1]=u.y*s; f[2]=u.z*s; f[3]=u.w*s;
    f[4]=v.x*s; f[5]=v.y*s; f[6]=v.z*s; f[7]=v.w*s;
  }else{
    uint4 r=*(const uint4*)((const u16*)base+idx);
    bld8(r,s,f);
  }
}
__device__ __forceinline__ float ld1(const void* base, int idx, int isf32){
  return isf32 ? ((const float*)base)[idx] : b2f((u32)((const u16*)base)[idx]);
}

// ---------------- K0: detect input dtype (0=bf16, 1=f32) ---------------------
__global__ __launch_bounds__(64) void k_detect(const u16* __restrict__ x, int* __restrict__ flag)
{
  __shared__ int w[64], z[64];
  const int t=threadIdx.x;
  int wild=0, zero=0;
  for(int i=t;i<256;i+=64){
    u32 u=(u32)x[2*i];
    u32 e=(u>>7)&0xFFu;
    if(e>=0x90u) wild++;
    if((u&0x7FFFu)==0u) zero++;
  }
  w[t]=wild; z[t]=zero; __syncthreads();
  if(t==0){
    int W=0,Z=0;
    for(int i=0;i<64;++i){W+=w[i];Z+=z[i];}
    flag[0]=(W>16||Z>200)?1:0;
  }
}

// ---------------- K0b: convert weights to bf16 (wb=[Wq;Wk;Wv], wob=Wo) ------
__global__ __launch_bounds__(256) void k_cvtw(const void* __restrict__ Wq,
    const void* __restrict__ Wk, const void* __restrict__ Wv, const void* __restrict__ Wo,
    u16* __restrict__ wb, u16* __restrict__ wob, const int* __restrict__ flagp)
{
  const int isf32=*flagp;
  const size_t WSZ=(size_t)DM*DM;
  size_t idx=((size_t)blockIdx.x*256+threadIdx.x)*8;
  const void* src; size_t off; u16* dst;
  if(idx<3*WSZ){ int w=(int)(idx/WSZ); src=(w==0)?Wq:((w==1)?Wk:Wv); off=idx-(size_t)w*WSZ; dst=wb+idx; }
  else { src=Wo; off=idx-3*WSZ; dst=wob+off; }
  if(isf32){
    const float* p=(const float*)src+off;
    float4 u=((const float4*)p)[0], v=((const float4*)p)[1];
    uint4 st;
    st.x=f2b(u.x)|(f2b(u.y)<<16); st.y=f2b(u.z)|(f2b(u.w)<<16);
    st.z=f2b(v.x)|(f2b(v.y)<<16); st.w=f2b(v.z)|(f2b(v.w)<<16);
    *(uint4*)dst=st;
  }else{
    *(uint4*)dst=*(const uint4*)((const u16*)src+off);
  }
}

// ---------------- K0c: pn = proj * NRM, bf16 [256][64] -----------------------
__global__ __launch_bounds__(256) void k_cvtp(const void* __restrict__ proj,
    u16* __restrict__ pn, const int* __restrict__ flagp)
{
  const int isf32=*flagp;
  const size_t idx=((size_t)blockIdx.x*256+threadIdx.x)*8;   // over 16384
  float pf[8];
  load8(proj, idx, isf32, NRM, pf);
  uint4 st;
  st.x=f2b(pf[0])|(f2b(pf[1])<<16); st.y=f2b(pf[2])|(f2b(pf[3])<<16);
  st.z=f2b(pf[4])|(f2b(pf[5])<<16); st.w=f2b(pf[6])|(f2b(pf[7])<<16);
  *(uint4*)(pn+idx)=st;
}

// ---------------- K0d: dk[bh*NS+n] = 0.5*NRM^2*sum(k^2) ----------------------
__global__ __launch_bounds__(256) void k_diag(const u16* __restrict__ kb, float* __restrict__ dk)
{
  const size_t row=(size_t)blockIdx.x*256+threadIdx.x;   // BH*NS rows
  const u16* p=kb+row*DH;
  float s=0.f;
#pragma unroll
  for(int c=0;c<DH;c+=8){
    uint4 r=*(const uint4*)(p+c);
    float f[8]; bld8(r,1.0f,f);
#pragma unroll
    for(int j=0;j<8;++j) s+=f[j]*f[j];
  }
  dk[row]=0.5f*NRM*NRM*s;
}

// ---------------- K1: MFMA GEMM  C[16384 x N] = A[16384x768] @ B[Nx768]^T ----
// mode 0: N=2304 -> q/k (head-interleaved [bh][n][d]) and v TRANSPOSED [bh][d][n]
// mode 1: N=768  -> d_out (+bo, dtype per flag)
__global__ __launch_bounds__(256) void k_gemm(const void* __restrict__ Araw,
    const u16* __restrict__ B16,
    const void* __restrict__ bias0, const void* __restrict__ bias1, const void* __restrict__ bias2,
    u16* __restrict__ q, u16* __restrict__ k, u16* __restrict__ v,
    void* __restrict__ outv, const int* __restrict__ flagp, const int mode)
{
  __shared__ short At[16*512];
  __shared__ short Bt[16*512];
  const int oflag=*flagp;
  const int isf32=(mode==0)?oflag:0;
  const int t=threadIdx.x, l=t&63, w=t>>6;
  const int m0=blockIdx.x*128, n0=blockIdx.y*128;
  const int wr4=(w>>1)*4, wc4=(w&1)*4;
  const int srow=l&15, skg=l>>4;
  floatx4 acc[4][4]={};
  for(int k0=0;k0<DM;k0+=64){
    __syncthreads();
#pragma unroll
    for(int s=0;s<4;++s){
      const int bi=w*4+s, rb=bi>>1, kh=bi&1;
      const int kc=k0+kh*32+skg*8;
      uint4 va;
      if(isf32){
        const float* ap=(const float*)Araw + (size_t)(m0+rb*16+srow)*DM + kc;
        float4 u=((const float4*)ap)[0], vv=((const float4*)ap)[1];
        va.x=f2b(u.x)|(f2b(u.y)<<16);  va.y=f2b(u.z)|(f2b(u.w)<<16);
        va.z=f2b(vv.x)|(f2b(vv.y)<<16); va.w=f2b(vv.z)|(f2b(vv.w)<<16);
      }else{
        va=*(const uint4*)((const u16*)Araw + (size_t)(m0+rb*16+srow)*DM + kc);
      }
      const uint4 vb=*(const uint4*)(B16 + (size_t)(n0+rb*16+srow)*DM + kc);
      *(uint4*)&At[bi*512+l*8]=va;
      *(uint4*)&Bt[bi*512+l*8]=vb;
    }
    __syncthreads();
#pragma unroll
    for(int kh=0;kh<2;++kh){
      short8 af[4], bf[4];
#pragma unroll
      for(int i=0;i<4;++i) af[i]=*(short8*)&At[((wr4+i)*2+kh)*512+l*8];
#pragma unroll
      for(int j=0;j<4;++j) bf[j]=*(short8*)&Bt[((wc4+j)*2+kh)*512+l*8];
#pragma unroll
      for(int i=0;i<4;++i)
#pragma unroll
        for(int j=0;j<4;++j)
          acc[i][j]=__builtin_amdgcn_mfma_f32_16x16x32_bf16(af[i],bf[j],acc[i][j],0,0,0);
    }
  }
  const int rbase=(l>>4)*4, cl=l&15;
  if(mode==0){
    const int which=n0/DM;
    const void* bias=(which==0)?bias0:((which==1)?bias1:bias2);
    u16* outp=(which==0)?q:((which==1)?k:v);
    const int cb=n0-which*DM;
#pragma unroll
    for(int j=0;j<4;++j){
      const int col=cb+(wc4+j)*16+cl;
      const int h=col>>6, dd=col&63;
      const float bb=ld1(bias,col,oflag);
#pragma unroll
      for(int i=0;i<4;++i){
#pragma unroll
        for(int r=0;r<4;++r){
          const int grow=m0+(wr4+i)*16+rbase+r;
          const int b_=grow>>11, n=grow&2047;
          const u16 val=(u16)f2b(acc[i][j][r]+bb);
          if(which==2) outp[((size_t)(b_*HN+h)*DH+dd)*NS + n]=val;       // vT [bh][d][n]
          else         outp[((size_t)((b_*HN+h)*NS+n))*DH + dd]=val;     // [bh][n][d]
        }
      }
    }
  }else{
#pragma unroll
    for(int j=0;j<4;++j){
      const int col=n0+(wc4+j)*16+cl;
      const float bb=ld1(bias0,col,oflag);
#pragma unroll
      for(int i=0;i<4;++i){
#pragma unroll
        for(int r=0;r<4;++r){
          const int grow=m0+(wr4+i)*16+rbase+r;
          const float val=acc[i][j][r]+bb;
          if(oflag) ((float*)outv)[(size_t)grow*DM+col]=val;
          else      ((u16*)outv)[(size_t)grow*DM+col]=(u16)f2b(val);
        }
      }
    }
  }
}

// ---------------- K2: MFMA xp_k + global max per bh --------------------------
// grid (NS/256, BH); block: 4 chunks of 64n x 256m, K=64
__global__ __launch_bounds__(256) void k_xpk2(const u16* __restrict__ kb,
    const u16* __restrict__ pn, u32* __restrict__ kmax)
{
  __shared__ short Bt[32*512];   // pn fragment order, 32 KB
  __shared__ short At[8*512];    // k chunk, 8 KB
  __shared__ float red[256];
  const int t=threadIdx.x, l=t&63, w=t>>6;
  const int bh=blockIdx.y, nb0=blockIdx.x*256;
  for(int s=t;s<2048;s+=256){
    const int ub=s>>6, l2=s&63, mt=ub>>1, kh=ub&1;
    const int row=mt*16+(l2&15), kc=kh*32+(l2>>4)*8;
    *(uint4*)&Bt[ub*512+l2*8]=*(const uint4*)(pn + (size_t)row*DH + kc);
  }
  float vmax=-3.4e38f;
  for(int c=0;c<4;++c){
    const int n0=nb0+c*64;
    __syncthreads();
    for(int s=t;s<512;s+=256){
      const int ua=s>>6, l2=s&63, rb=ua>>1, kh=ua&1;
      const int n=n0+rb*16+(l2&15), kc=kh*32+(l2>>4)*8;
      *(uint4*)&At[ua*512+l2*8]=*(const uint4*)(kb + ((size_t)bh*NS+n)*DH + kc);
    }
    __syncthreads();
    const short8 af0=*(short8*)&At[(w*2+0)*512+l*8];
    const short8 af1=*(short8*)&At[(w*2+1)*512+l*8];
#pragma unroll
    for(int mt=0;mt<16;++mt){
      floatx4 a={};
      a=__builtin_amdgcn_mfma_f32_16x16x32_bf16(af0,*(short8*)&Bt[(mt*2+0)*512+l*8],a,0,0,0);
      a=__builtin_amdgcn_mfma_f32_16x16x32_bf16(af1,*(short8*)&Bt[(mt*2+1)*512+l*8],a,0,0,0);
      vmax=fmaxf(vmax,fmaxf(fmaxf(a[0],a[1]),fmaxf(a[2],a[3])));
    }
  }
  red[t]=vmax; __syncthreads();
  for(int s=128;s>0;s>>=1){ if(t<s) red[t]=fmaxf(red[t],red[t+s]); __syncthreads(); }
  if(t==0) atomicMax(kmax+bh, fkey(red[0]));
}

// ---------------- K3: MFMA fused kp -> ksum + ctx ----------------------------
// grid (4 splits, BH); block: 8 chunks of 64n; ctx/ksum via atomicAdd
__global__ __launch_bounds__(256) void k_ctx2(const u16* __restrict__ kb,
    const u16* __restrict__ vT, const u16* __restrict__ pn,
    const float* __restrict__ dkbuf, const u32* __restrict__ kmax,
    float* __restrict__ ctx, float* __restrict__ ksum)
{
  __shared__ short Bt[32*512];     // pn fragment order, 32 KB
  __shared__ u16   Ks[256*72];     // kp^T [m][n], 36 KB (pad 72 for b128 align)
  __shared__ short AtV[8*512];     // k chunk, then v^T chunk, 8 KB
  __shared__ float dg[64];
  const int t=threadIdx.x, l=t&63, w=t>>6;
  const int split=blockIdx.x, bh=blockIdx.y;
  for(int s=t;s<2048;s+=256){
    const int ub=s>>6, l2=s&63, mt=ub>>1, kh=ub&1;
    const int row=mt*16+(l2&15), kc=kh*32+(l2>>4)*8;
    *(uint4*)&Bt[ub*512+l2*8]=*(const uint4*)(pn + (size_t)row*DH + kc);
  }
  const float kM=funkey(kmax[bh]);
  float ksr=0.f;
  floatx4 acc2[4][4]={};
  for(int c=0;c<8;++c){
    const int n0=split*512+c*64;
    __syncthreads();                                   // (1) prev phase2 readers done
    for(int s=t;s<512;s+=256){
      const int ua=s>>6, l2=s&63, rb=ua>>1, kh=ua&1;
      const int n=n0+rb*16+(l2&15), kc=kh*32+(l2>>4)*8;
      *(uint4*)&AtV[ua*512+l2*8]=*(const uint4*)(kb + ((size_t)bh*NS+n)*DH + kc);
    }
    if(t<64) dg[t]=dkbuf[(size_t)bh*NS+n0+t];
    __syncthreads();                                   // (2)
    // phase 1: wave w computes all 64 n x m-range [w*64, w*64+64)
    short8 af[4][2];
#pragma unroll
    for(int rb=0;rb<4;++rb){
      af[rb][0]=*(short8*)&AtV[(rb*2+0)*512+l*8];
      af[rb][1]=*(short8*)&AtV[(rb*2+1)*512+l*8];
    }
    float dgl[16];
#pragma unroll
    for(int rb=0;rb<4;++rb)
#pragma unroll
      for(int r=0;r<4;++r) dgl[rb*4+r]=dg[rb*16+(l>>4)*4+r];
#pragma unroll
    for(int ml=0;ml<4;++ml){
      const int mt=w*4+ml;
      const short8 bf0=*(short8*)&Bt[(mt*2+0)*512+l*8];
      const short8 bf1=*(short8*)&Bt[(mt*2+1)*512+l*8];
      const int m=mt*16+(l&15);
#pragma unroll
      for(int rb=0;rb<4;++rb){
        floatx4 a={};
        a=__builtin_amdgcn_mfma_f32_16x16x32_bf16(af[rb][0],bf0,a,0,0,0);
        a=__builtin_amdgcn_mfma_f32_16x16x32_bf16(af[rb][1],bf1,a,0,0,0);
        const int nb=rb*16+(l>>4)*4;
        const float v0=RATIO*(__expf(a[0]-dgl[rb*4+0]-kM)+EPSV);
        const float v1=RATIO*(__expf(a[1]-dgl[rb*4+1]-kM)+EPSV);
        const float v2=RATIO*(__expf(a[2]-dgl[rb*4+2]-kM)+EPSV);
        const float v3=RATIO*(__expf(a[3]-dgl[rb*4+3]-kM)+EPSV);
        *(u32*)&Ks[m*72+nb]  =f2b(v0)|(f2b(v1)<<16);
        *(u32*)&Ks[m*72+nb+2]=f2b(v2)|(f2b(v3)<<16);
      }
    }
    __syncthreads();                                   // (3) Ks done, AtV free
    for(int s=t;s<512;s+=256){
      const int uv=s>>6, l2=s&63, dt=uv>>1, kh=uv&1;
      const int d=dt*16+(l2&15), nn=n0+kh*32+(l2>>4)*8;
      *(uint4*)&AtV[uv*512+l2*8]=*(const uint4*)(vT + ((size_t)bh*DH+d)*NS + nn);
    }
    {
      float s8=0.f;
#pragma unroll
      for(int j=0;j<8;++j){
        const uint4 kk=*(const uint4*)&Ks[t*72+j*8];
        s8+=b2f(kk.x&0xffffu)+b2f(kk.x>>16)+b2f(kk.y&0xffffu)+b2f(kk.y>>16)
           +b2f(kk.z&0xffffu)+b2f(kk.z>>16)+b2f(kk.w&0xffffu)+b2f(kk.w>>16);
      }
      ksr+=s8;
    }
    __syncthreads();                                   // (4) Vt ready
    // phase 2: ctx[m][d] += kp^T @ v ; wave w: m-range [w*64, w*64+64)
#pragma unroll
    for(int i=0;i<4;++i){
      const int row=(w*4+i)*16+(l&15);
      const short8 a0=*(short8*)&Ks[row*72 + 0*32+(l>>4)*8];
      const short8 a1=*(short8*)&Ks[row*72 + 1*32+(l>>4)*8];
#pragma unroll
      for(int dt=0;dt<4;++dt){
        acc2[i][dt]=__builtin_amdgcn_mfma_f32_16x16x32_bf16(a0,*(short8*)&AtV[(dt*2+0)*512+l*8],acc2[i][dt],0,0,0);
        acc2[i][dt]=__builtin_amdgcn_mfma_f32_16x16x32_bf16(a1,*(short8*)&AtV[(dt*2+1)*512+l*8],acc2[i][dt],0,0,0);
      }
    }
  }
#pragma unroll
  for(int i=0;i<4;++i){
#pragma unroll
    for(int dt=0;dt<4;++dt){
#pragma unroll
      for(int r=0;r<4;++r){
        const int m=(w*4+i)*16+(l>>4)*4+r;
        const int d=dt*16+(l&15);
        atomicAdd(&ctx[((size_t)bh*MF+m)*DH+d], acc2[i][dt][r]);
      }
    }
  }
  atomicAdd(ksum+bh*MF+t, ksr);
}

// ---------------- K4: fused qp + D_inv + attn = D_inv*(qp@ctx) ---------------
__global__ __launch_bounds__(256) void k_attn_f(const u16* __restrict__ qb,
    const void* __restrict__ proj, const float* __restrict__ ksum,
    const float* __restrict__ ctx, u16* __restrict__ attn, const int* __restrict__ flagp)
{
  __shared__ float As[64][36];
  __shared__ u16   Bbuf[64*256];
  __shared__ float Cs[64*68];
  __shared__ float dinv_s[32];
  float* red   = Cs;
  float* rstat = Cs+1056;
  float* dstat = Cs+1088;
  float* ks    = Cs+1120;
  const int isf32=*flagp;
  const int t=threadIdx.x;
  const int bh=blockIdx.y, n0=blockIdx.x*32;
  {
    const int r=t>>3, c=(t&7)*8;
    uint4 a=*(const uint4*)(qb + ((size_t)bh*NS + n0 + r)*DH + c);
    float af[8]; bld8(a,NRM,af);
#pragma unroll
    for(int j=0;j<8;++j) As[c+j][r]=af[j];
  }
  {
    float pf[8];
#pragma unroll
    for(int c=0;c<64;c+=8){
      load8(proj,(size_t)t*DH+c,isf32,1.0f,pf);
#pragma unroll
      for(int j=0;j<8;++j) Bbuf[(c+j)*256+t]=(u16)f2b(pf[j]);
    }
  }
  ks[t]=ksum[bh*MF+t];
  __syncthreads();
  const int rg=(t>>5)*4, cg=(t&31)*4;
  float acc[4][8]={};
#pragma unroll
  for(int kk=0;kk<64;++kk){
    const float4 a4=*(const float4*)&As[kk][rg];
    const u16* prow=Bbuf+kk*256;
    const ushort4 b0=*(const ushort4*)(prow+cg);
    const ushort4 b1=*(const ushort4*)(prow+cg+128);
    const float av_[4]={a4.x,a4.y,a4.z,a4.w};
    const float bf0[4]={b2f((u32)b0.x),b2f((u32)b0.y),b2f((u32)b0.z),b2f((u32)b0.w)};
    const float bf1[4]={b2f((u32)b1.x),b2f((u32)b1.y),b2f((u32)b1.z),b2f((u32)b1.w)};
#pragma unroll
    for(int i=0;i<4;++i){
#pragma unroll
      for(int j=0;j<4;++j){ acc[i][j]+=av_[i]*bf0[j]; acc[i][4+j]+=av_[i]*bf1[j]; }
    }
  }
#pragma unroll
  for(int i=0;i<4;++i){
    float m=acc[i][0];
#pragma unroll
    for(int j=1;j<8;++j) m=fmaxf(m,acc[i][j]);
    red[(rg+i)*33+(t&31)]=m;
  }
  __syncthreads();
  if(t<32){
    float m=red[t*33];
#pragma unroll
    for(int j=1;j<32;++j) m=fmaxf(m,red[t*33+j]);
    rstat[t]=m;
    float d=0.f;
#pragma unroll
    for(int kk=0;kk<64;++kk){ float a=As[kk][t]; d+=a*a; }
    dstat[t]=0.5f*d;
  }
  __syncthreads();
  float qf[4][8], pd[4];
#pragma unroll
  for(int i=0;i<4;++i){
    const int r=rg+i;
    const float mm=rstat[r]+dstat[r];
    float p=0.f;
#pragma unroll
    for(int j=0;j<4;++j){ qf[i][j]  =RATIO*(__expf(acc[i][j]  -mm)+EPSV); p+=qf[i][j]  *ks[cg+j]; }
#pragma unroll
    for(int j=0;j<4;++j){ qf[i][4+j]=RATIO*(__expf(acc[i][4+j]-mm)+EPSV); p+=qf[i][4+j]*ks[128+cg+j]; }
    pd[i]=p;
  }
  __syncthreads();
#pragma unroll
  for(int i=0;i<4;++i){
#pragma unroll
    for(int j=0;j<4;++j){
      Bbuf[(cg+j)*36     + rg+i]=(u16)f2b(qf[i][j]);
      Bbuf[(128+cg+j)*36 + rg+i]=(u16)f2b(qf[i][4+j]);
    }
    red[(rg+i)*33+(t&31)]=pd[i];
  }
  __syncthreads();
  if(t<32){
    float s=red[t*33];
#pragma unroll
    for(int j=1;j<32;++j) s+=red[t*33+j];
    dinv_s[t]=1.0f/s;
  }
  const int tr2=(t>>5)*4, tc2=(t&31)*2;
  float acc2[4][2]={};
  for(int m0=0;m0<256;m0+=64){
    const float* cp = ctx + ((size_t)bh*MF + m0 + (t>>2))*DH + (t&3)*16;
    float4 c0=((const float4*)cp)[0], c1=((const float4*)cp)[1],
           c2=((const float4*)cp)[2], c3=((const float4*)cp)[3];
    __syncthreads();
    float* crow=Cs+(size_t)(t>>2)*68+(t&3)*16;
    ((float4*)crow)[0]=c0; ((float4*)crow)[1]=c1; ((float4*)crow)[2]=c2; ((float4*)crow)[3]=c3;
    __syncthreads();
#pragma unroll
    for(int mm=0;mm<64;++mm){
      const ushort4 a4=*(const ushort4*)(Bbuf+(m0+mm)*36+tr2);
      const float b0=Cs[mm*68+tc2], b1=Cs[mm*68+tc2+1];
      const float av_[4]={b2f((u32)a4.x),b2f((u32)a4.y),b2f((u32)a4.z),b2f((u32)a4.w)};
#pragma unroll
      for(int i=0;i<4;++i){ acc2[i][0]+=av_[i]*b0; acc2[i][1]+=av_[i]*b1; }
    }
  }
  const int b_=bh/HN, h=bh%HN;
#pragma unroll
  for(int i=0;i<4;++i){
    const int n=n0+tr2+i;
    const float sc=dinv_s[tr2+i];
    u32 st=f2b(acc2[i][0]*sc)|(f2b(acc2[i][1]*sc)<<16);
    *(u32*)(attn + ((size_t)(b_*NS+n))*DM + h*DH + tc2) = st;
  }
}

extern "C" void kernel_launch(void* const* d_in, const int* in_sizes, int n_in,
                              void* d_out, int out_size, void* d_ws, size_t ws_size,
                              hipStream_t stream)
{
  (void)in_sizes; (void)n_in; (void)out_size; (void)ws_size;
  const void* x =d_in[0];
  const void* Wq=d_in[1]; const void* bq=d_in[2];
  const void* Wk=d_in[3]; const void* bk=d_in[4];
  const void* Wv=d_in[5]; const void* bv=d_in[6];
  const void* Wo=d_in[7]; const void* bo=d_in[8];
  const void* proj=d_in[9];

  char* ws=(char*)d_ws;
  const size_t SZ=(size_t)BN*DM*2;               // 25,165,824 B
  u16*   qb  =(u16*)(ws);
  u16*   kb  =(u16*)(ws+SZ);
  u16*   vb  =(u16*)(ws+2*SZ);                   // holds v^T [bh][d][n]
  u16*   wb  =(u16*)(ws+3*SZ);                   // 3,538,944
  u16*   wob =(u16*)(ws+3*SZ+3538944);           // 1,179,648
  float* ctx =(float*)(ws+3*SZ+4718592);         // 6,291,456
  float* ksum=(float*)(ws+3*SZ+11010048);        // 98,304
  u32*   kmax=(u32*)(ws+3*SZ+11108352);          // 384
  int*   flag=(int*)(ws+3*SZ+11108736);          // pad to 128
  float* dk  =(float*)(ws+3*SZ+11108864);        // 786,432
  u16*   pn  =(u16*)(ws+3*SZ+11895296);          // 32,768
  u16*   attnb=kb;   // kb dead after k_ctx2
  // total ~87.4 MB

  k_detect<<<1,64,0,stream>>>((const u16*)x, flag);
  hipMemsetAsync(ctx, 0, 6291456+98304+384, stream);
  k_cvtw <<<1152, 256, 0, stream>>>(Wq,Wk,Wv,Wo,wb,wob,flag);
  k_cvtp <<<8, 256, 0, stream>>>(proj, pn, flag);
  k_gemm <<<dim3(BN/128,2304/128), 256, 0, stream>>>(x, wb, bq,bk,bv, qb,kb,vb, nullptr, flag, 0);
  k_diag <<<(BH*NS)/256, 256, 0, stream>>>(kb, dk);
  k_xpk2 <<<dim3(NS/256,BH), 256, 0, stream>>>(kb, pn, kmax);
  k_ctx2 <<<dim3(4,BH), 256, 0, stream>>>(kb, vb, pn, dk, kmax, ctx, ksum);
  k_attn_f<<<dim3(NS/32,BH), 256, 0, stream>>>(qb, proj, ksum, ctx, attnb, flag);
  k_gemm <<<dim3(BN/128,DM/128), 256, 0, stream>>>(attnb, wob, bo,bo,bo, nullptr,nullptr,nullptr, d_out, flag, 1);
}

// Round 5
// 655.692 us; speedup vs baseline: 3.3184x; 1.1860x over previous
//
#include <hip/hip_runtime.h>
#include <stdint.h>

typedef unsigned short u16;
typedef unsigned int u32;
typedef __attribute__((ext_vector_type(8))) short short8;
typedef __attribute__((ext_vector_type(4))) float floatx4;

#define HN 12
#define DH 64
#define DM 768
#define NS 2048
#define NB 8
#define MF 256
#define BN (NB*NS)
#define BH (NB*HN)

#define NRM 0.35355339059327373f  /* 64^-0.25 */
#define RATIO 0.0625f             /* 256^-0.5 */
#define EPSV 1e-4f

__device__ __forceinline__ float b2f(u32 u){ union{u32 i; float f;} x; x.i=u<<16; return x.f; }
__device__ __forceinline__ u32 f2b(float v){ union{float f; u32 u;} x; x.f=v; return (x.u + 0x7FFFu + ((x.u>>16)&1u))>>16; }
__device__ __forceinline__ u32 fkey(float v){ union{float f; u32 u;} x; x.f=v; return (x.u&0x80000000u)? ~x.u : (x.u|0x80000000u); }
__device__ __forceinline__ float funkey(u32 k){ union{u32 u; float f;} x; x.u=(k&0x80000000u)? (k^0x80000000u) : ~k; return x.f; }
__device__ __forceinline__ void bld8(uint4 r, float s, float* f){
  f[0]=b2f(r.x&0xffffu)*s; f[1]=b2f(r.x>>16)*s;
  f[2]=b2f(r.y&0xffffu)*s; f[3]=b2f(r.y>>16)*s;
  f[4]=b2f(r.z&0xffffu)*s; f[5]=b2f(r.z>>16)*s;
  f[6]=b2f(r.w&0xffffu)*s; f[7]=b2f(r.w>>16)*s;
}
__device__ __forceinline__ void load8(const void* base, size_t idx, int isf32, float s, float* f){
  if(isf32){
    const float* p=(const float*)base + idx;
    const float4 u=((const float4*)p)[0], v=((const float4*)p)[1];
    f[0]=u.x*s; f[1]=u.y*s; f[2]=u.z*s; f[3]=u.w*s;
    f[4]=v.x*s; f[5]=v.y*s; f[6]=v.z*s; f[7]=v.w*s;
  }else{
    uint4 r=*(const uint4*)((const u16*)base+idx);
    bld8(r,s,f);
  }
}
__device__ __forceinline__ float ld1(const void* base, int idx, int isf32){
  return isf32 ? ((const float*)base)[idx] : b2f((u32)((const u16*)base)[idx]);
}

// ---------------- K0: detect input dtype (0=bf16, 1=f32) ---------------------
__global__ __launch_bounds__(64) void k_detect(const u16* __restrict__ x, int* __restrict__ flag)
{
  __shared__ int w[64], z[64];
  const int t=threadIdx.x;
  int wild=0, zero=0;
  for(int i=t;i<256;i+=64){
    u32 u=(u32)x[2*i];
    u32 e=(u>>7)&0xFFu;
    if(e>=0x90u) wild++;
    if((u&0x7FFFu)==0u) zero++;
  }
  w[t]=wild; z[t]=zero; __syncthreads();
  if(t==0){
    int W=0,Z=0;
    for(int i=0;i<64;++i){W+=w[i];Z+=z[i];}
    flag[0]=(W>16||Z>200)?1:0;
  }
}

// ---------------- K0b: convert weights to bf16 (wb=[Wq;Wk;Wv], wob=Wo) ------
__global__ __launch_bounds__(256) void k_cvtw(const void* __restrict__ Wq,
    const void* __restrict__ Wk, const void* __restrict__ Wv, const void* __restrict__ Wo,
    u16* __restrict__ wb, u16* __restrict__ wob, const int* __restrict__ flagp)
{
  const int isf32=*flagp;
  const size_t WSZ=(size_t)DM*DM;
  size_t idx=((size_t)blockIdx.x*256+threadIdx.x)*8;
  const void* src; size_t off; u16* dst;
  if(idx<3*WSZ){ int w=(int)(idx/WSZ); src=(w==0)?Wq:((w==1)?Wk:Wv); off=idx-(size_t)w*WSZ; dst=wb+idx; }
  else { src=Wo; off=idx-3*WSZ; dst=wob+off; }
  if(isf32){
    const float* p=(const float*)src+off;
    float4 u=((const float4*)p)[0], v=((const float4*)p)[1];
    uint4 st;
    st.x=f2b(u.x)|(f2b(u.y)<<16); st.y=f2b(u.z)|(f2b(u.w)<<16);
    st.z=f2b(v.x)|(f2b(v.y)<<16); st.w=f2b(v.z)|(f2b(v.w)<<16);
    *(uint4*)dst=st;
  }else{
    *(uint4*)dst=*(const uint4*)((const u16*)src+off);
  }
}

// ---------------- K0c: pn = proj * NRM, bf16 [256][64] -----------------------
__global__ __launch_bounds__(256) void k_cvtp(const void* __restrict__ proj,
    u16* __restrict__ pn, const int* __restrict__ flagp)
{
  const int isf32=*flagp;
  const size_t idx=((size_t)blockIdx.x*256+threadIdx.x)*8;
  float pf[8];
  load8(proj, idx, isf32, NRM, pf);
  uint4 st;
  st.x=f2b(pf[0])|(f2b(pf[1])<<16); st.y=f2b(pf[2])|(f2b(pf[3])<<16);
  st.z=f2b(pf[4])|(f2b(pf[5])<<16); st.w=f2b(pf[6])|(f2b(pf[7])<<16);
  *(uint4*)(pn+idx)=st;
}

// ---------------- K0d: dk[row] = 0.5*NRM^2*sum(v^2) over DH ------------------
__global__ __launch_bounds__(256) void k_diag(const u16* __restrict__ src, float* __restrict__ dk)
{
  const size_t row=(size_t)blockIdx.x*256+threadIdx.x;
  const u16* p=src+row*DH;
  float s=0.f;
#pragma unroll
  for(int c=0;c<DH;c+=8){
    uint4 r=*(const uint4*)(p+c);
    float f[8]; bld8(r,1.0f,f);
#pragma unroll
    for(int j=0;j<8;++j) s+=f[j]*f[j];
  }
  dk[row]=0.5f*NRM*NRM*s;
}

// ---------------- K1: MFMA GEMM  C[16384 x N] = A[16384x768] @ B[Nx768]^T ----
__global__ __launch_bounds__(256) void k_gemm(const void* __restrict__ Araw,
    const u16* __restrict__ B16,
    const void* __restrict__ bias0, const void* __restrict__ bias1, const void* __restrict__ bias2,
    u16* __restrict__ q, u16* __restrict__ k, u16* __restrict__ v,
    void* __restrict__ outv, const int* __restrict__ flagp, const int mode)
{
  __shared__ short At[16*512];
  __shared__ short Bt[16*512];
  const int oflag=*flagp;
  const int isf32=(mode==0)?oflag:0;
  const int t=threadIdx.x, l=t&63, w=t>>6;
  const int m0=blockIdx.x*128, n0=blockIdx.y*128;
  const int wr4=(w>>1)*4, wc4=(w&1)*4;
  const int srow=l&15, skg=l>>4;
  floatx4 acc[4][4]={};
  for(int k0=0;k0<DM;k0+=64){
    __syncthreads();
#pragma unroll
    for(int s=0;s<4;++s){
      const int bi=w*4+s, rb=bi>>1, kh=bi&1;
      const int kc=k0+kh*32+skg*8;
      uint4 va;
      if(isf32){
        const float* ap=(const float*)Araw + (size_t)(m0+rb*16+srow)*DM + kc;
        float4 u=((const float4*)ap)[0], vv=((const float4*)ap)[1];
        va.x=f2b(u.x)|(f2b(u.y)<<16);  va.y=f2b(u.z)|(f2b(u.w)<<16);
        va.z=f2b(vv.x)|(f2b(vv.y)<<16); va.w=f2b(vv.z)|(f2b(vv.w)<<16);
      }else{
        va=*(const uint4*)((const u16*)Araw + (size_t)(m0+rb*16+srow)*DM + kc);
      }
      const uint4 vb=*(const uint4*)(B16 + (size_t)(n0+rb*16+srow)*DM + kc);
      *(uint4*)&At[bi*512+l*8]=va;
      *(uint4*)&Bt[bi*512+l*8]=vb;
    }
    __syncthreads();
#pragma unroll
    for(int kh=0;kh<2;++kh){
      short8 af[4], bf[4];
#pragma unroll
      for(int i=0;i<4;++i) af[i]=*(short8*)&At[((wr4+i)*2+kh)*512+l*8];
#pragma unroll
      for(int j=0;j<4;++j) bf[j]=*(short8*)&Bt[((wc4+j)*2+kh)*512+l*8];
#pragma unroll
      for(int i=0;i<4;++i)
#pragma unroll
        for(int j=0;j<4;++j)
          acc[i][j]=__builtin_amdgcn_mfma_f32_16x16x32_bf16(af[i],bf[j],acc[i][j],0,0,0);
    }
  }
  const int rbase=(l>>4)*4, cl=l&15;
  if(mode==0){
    const int which=n0/DM;
    const void* bias=(which==0)?bias0:((which==1)?bias1:bias2);
    u16* outp=(which==0)?q:((which==1)?k:v);
    const int cb=n0-which*DM;
#pragma unroll
    for(int j=0;j<4;++j){
      const int col=cb+(wc4+j)*16+cl;
      const int h=col>>6, dd=col&63;
      const float bb=ld1(bias,col,oflag);
#pragma unroll
      for(int i=0;i<4;++i){
#pragma unroll
        for(int r=0;r<4;++r){
          const int grow=m0+(wr4+i)*16+rbase+r;
          const int b_=grow>>11, n=grow&2047;
          const u16 val=(u16)f2b(acc[i][j][r]+bb);
          if(which==2) outp[((size_t)(b_*HN+h)*DH+dd)*NS + n]=val;       // vT [bh][d][n]
          else         outp[((size_t)((b_*HN+h)*NS+n))*DH + dd]=val;     // [bh][n][d]
        }
      }
    }
  }else{
#pragma unroll
    for(int j=0;j<4;++j){
      const int col=n0+(wc4+j)*16+cl;
      const float bb=ld1(bias0,col,oflag);
#pragma unroll
      for(int i=0;i<4;++i){
#pragma unroll
        for(int r=0;r<4;++r){
          const int grow=m0+(wr4+i)*16+rbase+r;
          const float val=acc[i][j][r]+bb;
          if(oflag) ((float*)outv)[(size_t)grow*DM+col]=val;
          else      ((u16*)outv)[(size_t)grow*DM+col]=(u16)f2b(val);
        }
      }
    }
  }
}

// ---------------- K2: MFMA xp_k + global max per bh --------------------------
__global__ __launch_bounds__(256) void k_xpk2(const u16* __restrict__ kb,
    const u16* __restrict__ pn, u32* __restrict__ kmax)
{
  __shared__ short Bt[32*512];
  __shared__ short At[8*512];
  __shared__ float red[256];
  const int t=threadIdx.x, l=t&63, w=t>>6;
  const int bh=blockIdx.y, nb0=blockIdx.x*256;
  for(int s=t;s<2048;s+=256){
    const int ub=s>>6, l2=s&63, mt=ub>>1, kh=ub&1;
    const int row=mt*16+(l2&15), kc=kh*32+(l2>>4)*8;
    *(uint4*)&Bt[ub*512+l2*8]=*(const uint4*)(pn + (size_t)row*DH + kc);
  }
  float vmax=-3.4e38f;
  for(int c=0;c<4;++c){
    const int n0=nb0+c*64;
    __syncthreads();
    for(int s=t;s<512;s+=256){
      const int ua=s>>6, l2=s&63, rb=ua>>1, kh=ua&1;
      const int n=n0+rb*16+(l2&15), kc=kh*32+(l2>>4)*8;
      *(uint4*)&At[ua*512+l2*8]=*(const uint4*)(kb + ((size_t)bh*NS+n)*DH + kc);
    }
    __syncthreads();
    const short8 af0=*(short8*)&At[(w*2+0)*512+l*8];
    const short8 af1=*(short8*)&At[(w*2+1)*512+l*8];
#pragma unroll
    for(int mt=0;mt<16;++mt){
      floatx4 a={};
      a=__builtin_amdgcn_mfma_f32_16x16x32_bf16(af0,*(short8*)&Bt[(mt*2+0)*512+l*8],a,0,0,0);
      a=__builtin_amdgcn_mfma_f32_16x16x32_bf16(af1,*(short8*)&Bt[(mt*2+1)*512+l*8],a,0,0,0);
      vmax=fmaxf(vmax,fmaxf(fmaxf(a[0],a[1]),fmaxf(a[2],a[3])));
    }
  }
  red[t]=vmax; __syncthreads();
  for(int s=128;s>0;s>>=1){ if(t<s) red[t]=fmaxf(red[t],red[t+s]); __syncthreads(); }
  if(t==0) atomicMax(kmax+bh, fkey(red[0]));
}

// ---------------- K3: MFMA fused kp -> ksum + ctx^T --------------------------
__global__ __launch_bounds__(256) void k_ctx2(const u16* __restrict__ kb,
    const u16* __restrict__ vT, const u16* __restrict__ pn,
    const float* __restrict__ dkbuf, const u32* __restrict__ kmax,
    float* __restrict__ ctxT, float* __restrict__ ksum)
{
  __shared__ short Bt[32*512];
  __shared__ u16   Ks[256*72];
  __shared__ short AtV[8*512];
  __shared__ float dg[64];
  const int t=threadIdx.x, l=t&63, w=t>>6;
  const int split=blockIdx.x, bh=blockIdx.y;
  for(int s=t;s<2048;s+=256){
    const int ub=s>>6, l2=s&63, mt=ub>>1, kh=ub&1;
    const int row=mt*16+(l2&15), kc=kh*32+(l2>>4)*8;
    *(uint4*)&Bt[ub*512+l2*8]=*(const uint4*)(pn + (size_t)row*DH + kc);
  }
  const float kM=funkey(kmax[bh]);
  float ksr=0.f;
  floatx4 acc2[4][4]={};
  for(int c=0;c<8;++c){
    const int n0=split*512+c*64;
    __syncthreads();
    for(int s=t;s<512;s+=256){
      const int ua=s>>6, l2=s&63, rb=ua>>1, kh=ua&1;
      const int n=n0+rb*16+(l2&15), kc=kh*32+(l2>>4)*8;
      *(uint4*)&AtV[ua*512+l2*8]=*(const uint4*)(kb + ((size_t)bh*NS+n)*DH + kc);
    }
    if(t<64) dg[t]=dkbuf[(size_t)bh*NS+n0+t];
    __syncthreads();
    short8 af[4][2];
#pragma unroll
    for(int rb=0;rb<4;++rb){
      af[rb][0]=*(short8*)&AtV[(rb*2+0)*512+l*8];
      af[rb][1]=*(short8*)&AtV[(rb*2+1)*512+l*8];
    }
    float dgl[16];
#pragma unroll
    for(int rb=0;rb<4;++rb)
#pragma unroll
      for(int r=0;r<4;++r) dgl[rb*4+r]=dg[rb*16+(l>>4)*4+r];
#pragma unroll
    for(int ml=0;ml<4;++ml){
      const int mt=w*4+ml;
      const short8 bf0=*(short8*)&Bt[(mt*2+0)*512+l*8];
      const short8 bf1=*(short8*)&Bt[(mt*2+1)*512+l*8];
      const int m=mt*16+(l&15);
#pragma unroll
      for(int rb=0;rb<4;++rb){
        floatx4 a={};
        a=__builtin_amdgcn_mfma_f32_16x16x32_bf16(af[rb][0],bf0,a,0,0,0);
        a=__builtin_amdgcn_mfma_f32_16x16x32_bf16(af[rb][1],bf1,a,0,0,0);
        const int nb=rb*16+(l>>4)*4;
        const float v0=RATIO*(__expf(a[0]-dgl[rb*4+0]-kM)+EPSV);
        const float v1=RATIO*(__expf(a[1]-dgl[rb*4+1]-kM)+EPSV);
        const float v2=RATIO*(__expf(a[2]-dgl[rb*4+2]-kM)+EPSV);
        const float v3=RATIO*(__expf(a[3]-dgl[rb*4+3]-kM)+EPSV);
        *(u32*)&Ks[m*72+nb]  =f2b(v0)|(f2b(v1)<<16);
        *(u32*)&Ks[m*72+nb+2]=f2b(v2)|(f2b(v3)<<16);
      }
    }
    __syncthreads();
    for(int s=t;s<512;s+=256){
      const int uv=s>>6, l2=s&63, dt=uv>>1, kh=uv&1;
      const int d=dt*16+(l2&15), nn=n0+kh*32+(l2>>4)*8;
      *(uint4*)&AtV[uv*512+l2*8]=*(const uint4*)(vT + ((size_t)bh*DH+d)*NS + nn);
    }
    {
      float s8=0.f;
#pragma unroll
      for(int j=0;j<8;++j){
        const uint4 kk=*(const uint4*)&Ks[t*72+j*8];
        s8+=b2f(kk.x&0xffffu)+b2f(kk.x>>16)+b2f(kk.y&0xffffu)+b2f(kk.y>>16)
           +b2f(kk.z&0xffffu)+b2f(kk.z>>16)+b2f(kk.w&0xffffu)+b2f(kk.w>>16);
      }
      ksr+=s8;
    }
    __syncthreads();
#pragma unroll
    for(int i=0;i<4;++i){
      const int row=(w*4+i)*16+(l&15);
      const short8 a0=*(short8*)&Ks[row*72 + 0*32+(l>>4)*8];
      const short8 a1=*(short8*)&Ks[row*72 + 1*32+(l>>4)*8];
#pragma unroll
      for(int dt=0;dt<4;++dt){
        acc2[i][dt]=__builtin_amdgcn_mfma_f32_16x16x32_bf16(a0,*(short8*)&AtV[(dt*2+0)*512+l*8],acc2[i][dt],0,0,0);
        acc2[i][dt]=__builtin_amdgcn_mfma_f32_16x16x32_bf16(a1,*(short8*)&AtV[(dt*2+1)*512+l*8],acc2[i][dt],0,0,0);
      }
    }
  }
#pragma unroll
  for(int i=0;i<4;++i){
#pragma unroll
    for(int dt=0;dt<4;++dt){
#pragma unroll
      for(int r=0;r<4;++r){
        const int m=(w*4+i)*16+(l>>4)*4+r;
        const int d=dt*16+(l&15);
        atomicAdd(&ctxT[((size_t)bh*DH+d)*MF+m], acc2[i][dt][r]);   // transposed [d][m]
      }
    }
  }
  atomicAdd(ksum+bh*MF+t, ksr);
}

// ---------------- K3b: split ctxT f32 -> hi/lo bf16, ecs=eps*colsum ----------
__global__ __launch_bounds__(256) void k_csplit(const float* __restrict__ ctxT,
    u16* __restrict__ chi, u16* __restrict__ clo, float* __restrict__ ecs)
{
  __shared__ float cred[256];
  const int bh=blockIdx.x, t=threadIdx.x;
  const int d=t>>2, part=t&3;
  const size_t base=((size_t)bh*DH+d)*MF + part*64;
  const float* src=ctxT + base;
  u16* ph=chi + base;
  u16* pl=clo + base;
  float cs=0.f;
  for(int m=0;m<64;m+=4){
    float4 v=*(const float4*)(src+m);
    float vv[4]={v.x,v.y,v.z,v.w};
    u32 h_[4], l_[4];
#pragma unroll
    for(int j=0;j<4;++j){
      cs+=vv[j];
      u32 hh=f2b(vv[j]);
      float rr=vv[j]-b2f(hh);
      h_[j]=hh; l_[j]=f2b(rr);
    }
    uint2 sh, sl;
    sh.x=h_[0]|(h_[1]<<16); sh.y=h_[2]|(h_[3]<<16);
    sl.x=l_[0]|(l_[1]<<16); sl.y=l_[2]|(l_[3]<<16);
    *(uint2*)(ph+m)=sh; *(uint2*)(pl+m)=sl;
  }
  cred[t]=cs; __syncthreads();
  if(part==0) ecs[bh*64+d]=EPSV*(cred[t]+cred[t+1]+cred[t+2]+cred[t+3]);
}

// ---------------- K4: MFMA fused qp + D_inv + attn ---------------------------
// grid (NS/256, BH); per 64n chunk: phase1 xp^T->E->Qf(frag layout), phase2 E@ctx
__global__ __launch_bounds__(256) void k_attn2(const u16* __restrict__ qb,
    const u16* __restrict__ pn, const float* __restrict__ dqbuf,
    const float* __restrict__ ksum, const u16* __restrict__ chi, const u16* __restrict__ clo,
    const float* __restrict__ ecs, u16* __restrict__ attn)
{
  __shared__ short At[8*512];     // q chunk fragments (B-operand), 8 KB
  __shared__ u16 Qf[32*512];      // E fragments (A-operand for phase2), 32 KB
  __shared__ float ksums[256];
  __shared__ float dq_s[64];
  __shared__ float mxs[4][64];
  __shared__ float s1s[4][64];
  __shared__ float a_s[64], dinv_s[64], ec_s[64];
  __shared__ float red4[4];
  __shared__ float epkss;
  const int t=threadIdx.x, l=t&63, w=t>>6;
  const int bh=blockIdx.y, nb0=blockIdx.x*256;
  const int b_=bh/HN, h=bh%HN;
  {
    float kv=ksum[bh*MF+t];
    ksums[t]=kv;
    if(t<64) ec_s[t]=ecs[bh*64+t];
    float s=kv;
#pragma unroll
    for(int o=1;o<64;o<<=1) s+=__shfl_xor(s,o,64);
    if(l==0) red4[w]=s;
  }
  __syncthreads();
  if(t==0) epkss=EPSV*(red4[0]+red4[1]+red4[2]+red4[3]);
  // phase2 B fragments (ctx^T hi/lo), held in regs for all chunks
  short8 bhf[8], blf[8];
  {
    const int d=w*16+(l&15);
    const size_t base=((size_t)bh*DH+d)*MF;
#pragma unroll
    for(int kc=0;kc<8;++kc){
      const size_t off=base + kc*32+(l>>4)*8;
      bhf[kc]=*(const short8*)(chi+off);
      blf[kc]=*(const short8*)(clo+off);
    }
  }
  for(int c=0;c<4;++c){
    const int n0c=nb0+c*64;
    __syncthreads();                               // prev-chunk Qf reads done
    for(int s=t;s<512;s+=256){
      const int ua=s>>6, l2=s&63, nt=ua>>1, kh=ua&1;
      const int n=n0c+nt*16+(l2&15), kc=kh*32+(l2>>4)*8;
      *(uint4*)&At[ua*512+l2*8]=*(const uint4*)(qb + ((size_t)bh*NS+n)*DH + kc);
    }
    if(t<64) dq_s[t]=dqbuf[(size_t)bh*NS+n0c+t];
    __syncthreads();
    // phase 1: xp^T = pn(m rows) @ q(n cols); wave w -> m strip [w*64,w*64+64)
    float mxl[4]={-3.4e38f,-3.4e38f,-3.4e38f,-3.4e38f};
    float s1l[4]={0.f,0.f,0.f,0.f};
#pragma unroll
    for(int mt=0;mt<4;++mt){
      const int gm=w*4+mt;
      const u16* pr=pn + ((gm*16+(l&15))<<6) + (l>>4)*8;
      const short8 a0=*(const short8*)(pr);
      const short8 a1=*(const short8*)(pr+32);
      float k4[4];
#pragma unroll
      for(int r=0;r<4;++r) k4[r]=ksums[gm*16+(l>>4)*4+r];
      const int mbase=(gm&1)*16+(l>>4)*4;
      const int lane2=((mbase>>3)*16+(l&15))*8 + (mbase&7);
#pragma unroll
      for(int nt=0;nt<4;++nt){
        floatx4 xp={};
        xp=__builtin_amdgcn_mfma_f32_16x16x32_bf16(a0,*(short8*)&At[(nt*2+0)*512+l*8],xp,0,0,0);
        xp=__builtin_amdgcn_mfma_f32_16x16x32_bf16(a1,*(short8*)&At[(nt*2+1)*512+l*8],xp,0,0,0);
        const float dq=dq_s[nt*16+(l&15)];
        float ev[4];
#pragma unroll
        for(int r=0;r<4;++r){
          const float xv=xp[r];
          mxl[nt]=fmaxf(mxl[nt],xv);
          ev[r]=__expf(xv-dq);
          s1l[nt]+=ev[r]*k4[r];
        }
        u16* qp_=&Qf[(nt*8+(gm>>1))*512 + lane2];
        *(u32*)qp_    =f2b(ev[0])|(f2b(ev[1])<<16);
        *(u32*)(qp_+2)=f2b(ev[2])|(f2b(ev[3])<<16);
      }
    }
#pragma unroll
    for(int nt=0;nt<4;++nt){
      float m_=mxl[nt], s_=s1l[nt];
      m_=fmaxf(m_,__shfl_xor(m_,16,64)); s_+=__shfl_xor(s_,16,64);
      m_=fmaxf(m_,__shfl_xor(m_,32,64)); s_+=__shfl_xor(s_,32,64);
      if(l<16){ mxs[w][nt*16+l]=m_; s1s[w][nt*16+l]=s_; }
    }
    __syncthreads();                               // Qf + mxs/s1s ready
    if(t<64){
      float m_=fmaxf(fmaxf(mxs[0][t],mxs[1][t]),fmaxf(mxs[2][t],mxs[3][t]));
      float s_=s1s[0][t]+s1s[1][t]+s1s[2][t]+s1s[3][t];
      float a=__expf(-m_);
      a_s[t]=a;
      dinv_s[t]=1.0f/(a*s_+epkss);
    }
    __syncthreads();
    // phase 2: attn[n][d] = E @ ctx ; wave w -> d strip [w*16,w*16+16)
    const int d=w*16+(l&15);
    const float ec=ec_s[d];
#pragma unroll
    for(int nt=0;nt<4;++nt){
      floatx4 y={};
#pragma unroll
      for(int kc=0;kc<8;++kc){
        const short8 e=*(short8*)&Qf[(nt*8+kc)*512+l*8];
        y=__builtin_amdgcn_mfma_f32_16x16x32_bf16(e,bhf[kc],y,0,0,0);
        y=__builtin_amdgcn_mfma_f32_16x16x32_bf16(e,blf[kc],y,0,0,0);
      }
#pragma unroll
      for(int r=0;r<4;++r){
        const int nl=nt*16+(l>>4)*4+r;
        const float val=(a_s[nl]*y[r]+ec)*dinv_s[nl];
        attn[((size_t)(b_*NS+n0c+nl))*DM + h*DH + d]=(u16)f2b(val);
      }
    }
  }
}

extern "C" void kernel_launch(void* const* d_in, const int* in_sizes, int n_in,
                              void* d_out, int out_size, void* d_ws, size_t ws_size,
                              hipStream_t stream)
{
  (void)in_sizes; (void)n_in; (void)out_size; (void)ws_size;
  const void* x =d_in[0];
  const void* Wq=d_in[1]; const void* bq=d_in[2];
  const void* Wk=d_in[3]; const void* bk=d_in[4];
  const void* Wv=d_in[5]; const void* bv=d_in[6];
  const void* Wo=d_in[7]; const void* bo=d_in[8];
  const void* proj=d_in[9];

  char* ws=(char*)d_ws;
  const size_t SZ=(size_t)BN*DM*2;               // 25,165,824 B
  u16*   qb  =(u16*)(ws);
  u16*   kb  =(u16*)(ws+SZ);
  u16*   vb  =(u16*)(ws+2*SZ);                   // v^T [bh][d][n]
  char*  aux =ws+3*SZ;
  u16*   wb   =(u16*)(aux);                      // 3,538,944
  u16*   wob  =(u16*)(aux+3538944);              // 1,179,648 -> 4,718,592
  float* ctxT =(float*)(aux+4718592);            // 6,291,456 -> 11,010,048
  float* ksum =(float*)(aux+11010048);           // 98,304    -> 11,108,352
  u32*   kmax =(u32*)(aux+11108352);             // 384       -> 11,108,736
  int*   flag =(int*)(aux+11108736);             // 128       -> 11,108,864
  float* dk   =(float*)(aux+11108864);           // 786,432   -> 11,895,296
  float* dqq  =(float*)(aux+11895296);           // 786,432   -> 12,681,728
  u16*   pn   =(u16*)(aux+12681728);             // 32,768    -> 12,714,496
  u16*   chi  =(u16*)(aux+12714496);             // 3,145,728 -> 15,860,224
  u16*   clo  =(u16*)(aux+15860224);             // 3,145,728 -> 19,005,952
  float* ecs  =(float*)(aux+19005952);           // 24,576    -> 19,030,528
  u16*   attnb=kb;                               // kb dead after k_ctx2
  // total ~94.5 MB

  k_detect<<<1,64,0,stream>>>((const u16*)x, flag);
  hipMemsetAsync(ctxT, 0, 6291456+98304+384, stream);
  k_cvtw <<<1152, 256, 0, stream>>>(Wq,Wk,Wv,Wo,wb,wob,flag);
  k_cvtp <<<8, 256, 0, stream>>>(proj, pn, flag);
  k_gemm <<<dim3(BN/128,2304/128), 256, 0, stream>>>(x, wb, bq,bk,bv, qb,kb,vb, nullptr, flag, 0);
  k_diag <<<(BH*NS)/256, 256, 0, stream>>>(kb, dk);
  k_diag <<<(BH*NS)/256, 256, 0, stream>>>(qb, dqq);
  k_xpk2 <<<dim3(NS/256,BH), 256, 0, stream>>>(kb, pn, kmax);
  k_ctx2 <<<dim3(4,BH), 256, 0, stream>>>(kb, vb, pn, dk, kmax, ctxT, ksum);
  k_csplit<<<BH, 256, 0, stream>>>(ctxT, chi, clo, ecs);
  k_attn2<<<dim3(NS/256,BH), 256, 0, stream>>>(qb, pn, dqq, ksum, chi, clo, ecs, attnb);
  k_gemm <<<dim3(BN/128,DM/128), 256, 0, stream>>>(attnb, wob, bo,bo,bo, nullptr,nullptr,nullptr, d_out, flag, 1);
}

// Round 6
// 546.396 us; speedup vs baseline: 3.9822x; 1.2000x over previous
//
#include <hip/hip_runtime.h>
#include <stdint.h>

typedef unsigned short u16;
typedef unsigned int u32;
typedef __attribute__((ext_vector_type(8))) short short8;
typedef __attribute__((ext_vector_type(4))) float floatx4;

#define HN 12
#define DH 64
#define DM 768
#define NS 2048
#define NB 8
#define MF 256
#define BN (NB*NS)
#define BH (NB*HN)

#define NRM 0.35355339059327373f  /* 64^-0.25 */
#define RATIO 0.0625f             /* 256^-0.5 */
#define EPSV 1e-4f

__device__ __forceinline__ float b2f(u32 u){ union{u32 i; float f;} x; x.i=u<<16; return x.f; }
__device__ __forceinline__ u32 f2b(float v){ union{float f; u32 u;} x; x.f=v; return (x.u + 0x7FFFu + ((x.u>>16)&1u))>>16; }
__device__ __forceinline__ u32 fkey(float v){ union{float f; u32 u;} x; x.f=v; return (x.u&0x80000000u)? ~x.u : (x.u|0x80000000u); }
__device__ __forceinline__ float funkey(u32 k){ union{u32 u; float f;} x; x.u=(k&0x80000000u)? (k^0x80000000u) : ~k; return x.f; }
__device__ __forceinline__ void bld8(uint4 r, float s, float* f){
  f[0]=b2f(r.x&0xffffu)*s; f[1]=b2f(r.x>>16)*s;
  f[2]=b2f(r.y&0xffffu)*s; f[3]=b2f(r.y>>16)*s;
  f[4]=b2f(r.z&0xffffu)*s; f[5]=b2f(r.z>>16)*s;
  f[6]=b2f(r.w&0xffffu)*s; f[7]=b2f(r.w>>16)*s;
}
__device__ __forceinline__ void load8(const void* base, size_t idx, int isf32, float s, float* f){
  if(isf32){
    const float* p=(const float*)base + idx;
    const float4 u=((const float4*)p)[0], v=((const float4*)p)[1];
    f[0]=u.x*s; f[1]=u.y*s; f[2]=u.z*s; f[3]=u.w*s;
    f[4]=v.x*s; f[5]=v.y*s; f[6]=v.z*s; f[7]=v.w*s;
  }else{
    uint4 r=*(const uint4*)((const u16*)base+idx);
    bld8(r,s,f);
  }
}
__device__ __forceinline__ float ld1(const void* base, int idx, int isf32){
  return isf32 ? ((const float*)base)[idx] : b2f((u32)((const u16*)base)[idx]);
}
// async global->LDS, 16B/lane; l must be wave-uniform, data lands at l + lane*16B
__device__ __forceinline__ void gl16(const void* g, void* l){
  __builtin_amdgcn_global_load_lds(
    (const __attribute__((address_space(1))) u32*)g,
    (__attribute__((address_space(3))) u32*)l, 16, 0, 0);
}

// ---------------- K0: detect input dtype (0=bf16, 1=f32) ---------------------
__global__ __launch_bounds__(64) void k_detect(const u16* __restrict__ x, int* __restrict__ flag)
{
  __shared__ int w[64], z[64];
  const int t=threadIdx.x;
  int wild=0, zero=0;
  for(int i=t;i<256;i+=64){
    u32 u=(u32)x[2*i];
    u32 e=(u>>7)&0xFFu;
    if(e>=0x90u) wild++;
    if((u&0x7FFFu)==0u) zero++;
  }
  w[t]=wild; z[t]=zero; __syncthreads();
  if(t==0){
    int W=0,Z=0;
    for(int i=0;i<64;++i){W+=w[i];Z+=z[i];}
    flag[0]=(W>16||Z>200)?1:0;
  }
}

// ---------------- K0b: convert weights to bf16 (wb=[Wq;Wk;Wv], wob=Wo) ------
__global__ __launch_bounds__(256) void k_cvtw(const void* __restrict__ Wq,
    const void* __restrict__ Wk, const void* __restrict__ Wv, const void* __restrict__ Wo,
    u16* __restrict__ wb, u16* __restrict__ wob, const int* __restrict__ flagp)
{
  const int isf32=*flagp;
  const size_t WSZ=(size_t)DM*DM;
  size_t idx=((size_t)blockIdx.x*256+threadIdx.x)*8;
  const void* src; size_t off; u16* dst;
  if(idx<3*WSZ){ int w=(int)(idx/WSZ); src=(w==0)?Wq:((w==1)?Wk:Wv); off=idx-(size_t)w*WSZ; dst=wb+idx; }
  else { src=Wo; off=idx-3*WSZ; dst=wob+off; }
  if(isf32){
    const float* p=(const float*)src+off;
    float4 u=((const float4*)p)[0], v=((const float4*)p)[1];
    uint4 st;
    st.x=f2b(u.x)|(f2b(u.y)<<16); st.y=f2b(u.z)|(f2b(u.w)<<16);
    st.z=f2b(v.x)|(f2b(v.y)<<16); st.w=f2b(v.z)|(f2b(v.w)<<16);
    *(uint4*)dst=st;
  }else{
    *(uint4*)dst=*(const uint4*)((const u16*)src+off);
  }
}

// ---------------- K0c: pn = proj * NRM, bf16 [256][64] -----------------------
__global__ __launch_bounds__(256) void k_cvtp(const void* __restrict__ proj,
    u16* __restrict__ pn, const int* __restrict__ flagp)
{
  const int isf32=*flagp;
  const size_t idx=((size_t)blockIdx.x*256+threadIdx.x)*8;
  float pf[8];
  load8(proj, idx, isf32, NRM, pf);
  uint4 st;
  st.x=f2b(pf[0])|(f2b(pf[1])<<16); st.y=f2b(pf[2])|(f2b(pf[3])<<16);
  st.z=f2b(pf[4])|(f2b(pf[5])<<16); st.w=f2b(pf[6])|(f2b(pf[7])<<16);
  *(uint4*)(pn+idx)=st;
}

// ---------------- K0e: xb = bf16(x) ------------------------------------------
__global__ __launch_bounds__(256) void k_cvtx(const void* __restrict__ x,
    u16* __restrict__ xb, const int* __restrict__ flagp)
{
  const int isf32=*flagp;
  const size_t idx=((size_t)blockIdx.x*256+threadIdx.x)*8;   // over BN*DM
  float f[8];
  load8(x, idx, isf32, 1.0f, f);
  uint4 st;
  st.x=f2b(f[0])|(f2b(f[1])<<16); st.y=f2b(f[2])|(f2b(f[3])<<16);
  st.z=f2b(f[4])|(f2b(f[5])<<16); st.w=f2b(f[6])|(f2b(f[7])<<16);
  *(uint4*)(xb+idx)=st;
}

// ---------------- K0d: dk[row] = 0.5*NRM^2*sum(v^2) over DH ------------------
__global__ __launch_bounds__(256) void k_diag(const u16* __restrict__ src, float* __restrict__ dk)
{
  const size_t row=(size_t)blockIdx.x*256+threadIdx.x;
  const u16* p=src+row*DH;
  float s=0.f;
#pragma unroll
  for(int c=0;c<DH;c+=8){
    uint4 r=*(const uint4*)(p+c);
    float f[8]; bld8(r,1.0f,f);
#pragma unroll
    for(int j=0;j<8;++j) s+=f[j]*f[j];
  }
  dk[row]=0.5f*NRM*NRM*s;
}

// ======== shared epilogue for the two MFMA GEMMs =============================
__device__ __forceinline__ void gemm_epilogue(const floatx4 acc[4][4], int mode, int oflag,
    int m0, int n0, int l, int wr4, int wc4,
    const void* bias0, const void* bias1, const void* bias2,
    u16* q, u16* k, u16* v, void* outv)
{
  const int rbase=(l>>4)*4, cl=l&15;
  if(mode==0){
    const int which=n0/DM;
    const void* bias=(which==0)?bias0:((which==1)?bias1:bias2);
    u16* outp=(which==0)?q:((which==1)?k:v);
    const int cb=n0-which*DM;
#pragma unroll
    for(int j=0;j<4;++j){
      const int col=cb+(wc4+j)*16+cl;
      const int h=col>>6, dd=col&63;
      const float bb=ld1(bias,col,oflag);
#pragma unroll
      for(int i=0;i<4;++i){
#pragma unroll
        for(int r=0;r<4;++r){
          const int grow=m0+(wr4+i)*16+rbase+r;
          const int b_=grow>>11, n=grow&2047;
          const u16 val=(u16)f2b(acc[i][j][r]+bb);
          if(which==2) outp[((size_t)(b_*HN+h)*DH+dd)*NS + n]=val;       // vT [bh][d][n]
          else         outp[((size_t)((b_*HN+h)*NS+n))*DH + dd]=val;     // [bh][n][d]
        }
      }
    }
  }else{
#pragma unroll
    for(int j=0;j<4;++j){
      const int col=n0+(wc4+j)*16+cl;
      const float bb=ld1(bias0,col,oflag);
#pragma unroll
      for(int i=0;i<4;++i){
#pragma unroll
        for(int r=0;r<4;++r){
          const int grow=m0+(wr4+i)*16+rbase+r;
          const float val=acc[i][j][r]+bb;
          if(oflag) ((float*)outv)[(size_t)grow*DM+col]=val;
          else      ((u16*)outv)[(size_t)grow*DM+col]=(u16)f2b(val);
        }
      }
    }
  }
}

// ---------------- K1: MFMA GEMM, bf16 A, global_load_lds staging -------------
__global__ __launch_bounds__(256) void k_gemm2(const u16* __restrict__ A16,
    const u16* __restrict__ B16,
    const void* __restrict__ bias0, const void* __restrict__ bias1, const void* __restrict__ bias2,
    u16* __restrict__ q, u16* __restrict__ k, u16* __restrict__ v,
    void* __restrict__ outv, const int* __restrict__ flagp, const int mode)
{
  __shared__ short At[16*512];
  __shared__ short Bt[16*512];
  const int oflag=*flagp;
  const int t=threadIdx.x, l=t&63, w=t>>6;
  const int m0=blockIdx.x*128, n0=blockIdx.y*128;
  const int wr4=(w>>1)*4, wc4=(w&1)*4;
  const int srow=l&15, skg=l>>4;
  floatx4 acc[4][4]={};
  for(int k0=0;k0<DM;k0+=64){
    __syncthreads();
#pragma unroll
    for(int s=0;s<4;++s){
      const int bi=w*4+s, rb=bi>>1, kh=bi&1;
      const int kc=k0+kh*32+skg*8;
      gl16(A16 + (size_t)(m0+rb*16+srow)*DM + kc, &At[bi*512]);
      gl16(B16 + (size_t)(n0+rb*16+srow)*DM + kc, &Bt[bi*512]);
    }
    __syncthreads();
#pragma unroll
    for(int kh=0;kh<2;++kh){
      short8 af[4], bf[4];
#pragma unroll
      for(int i=0;i<4;++i) af[i]=*(short8*)&At[((wr4+i)*2+kh)*512+l*8];
#pragma unroll
      for(int j=0;j<4;++j) bf[j]=*(short8*)&Bt[((wc4+j)*2+kh)*512+l*8];
#pragma unroll
      for(int i=0;i<4;++i)
#pragma unroll
        for(int j=0;j<4;++j)
          acc[i][j]=__builtin_amdgcn_mfma_f32_16x16x32_bf16(af[i],bf[j],acc[i][j],0,0,0);
    }
  }
  gemm_epilogue(acc,mode,oflag,m0,n0,l,wr4,wc4,bias0,bias1,bias2,q,k,v,outv);
}

// ---------------- K1f: fallback MFMA GEMM, f32-capable A (round-5 path) ------
__global__ __launch_bounds__(256) void k_gemm_f(const void* __restrict__ Araw,
    const u16* __restrict__ B16,
    const void* __restrict__ bias0, const void* __restrict__ bias1, const void* __restrict__ bias2,
    u16* __restrict__ q, u16* __restrict__ k, u16* __restrict__ v,
    void* __restrict__ outv, const int* __restrict__ flagp, const int mode)
{
  __shared__ short At[16*512];
  __shared__ short Bt[16*512];
  const int oflag=*flagp;
  const int isf32=(mode==0)?oflag:0;
  const int t=threadIdx.x, l=t&63, w=t>>6;
  const int m0=blockIdx.x*128, n0=blockIdx.y*128;
  const int wr4=(w>>1)*4, wc4=(w&1)*4;
  const int srow=l&15, skg=l>>4;
  floatx4 acc[4][4]={};
  for(int k0=0;k0<DM;k0+=64){
    __syncthreads();
#pragma unroll
    for(int s=0;s<4;++s){
      const int bi=w*4+s, rb=bi>>1, kh=bi&1;
      const int kc=k0+kh*32+skg*8;
      uint4 va;
      if(isf32){
        const float* ap=(const float*)Araw + (size_t)(m0+rb*16+srow)*DM + kc;
        float4 u=((const float4*)ap)[0], vv=((const float4*)ap)[1];
        va.x=f2b(u.x)|(f2b(u.y)<<16);  va.y=f2b(u.z)|(f2b(u.w)<<16);
        va.z=f2b(vv.x)|(f2b(vv.y)<<16); va.w=f2b(vv.z)|(f2b(vv.w)<<16);
      }else{
        va=*(const uint4*)((const u16*)Araw + (size_t)(m0+rb*16+srow)*DM + kc);
      }
      const uint4 vb=*(const uint4*)(B16 + (size_t)(n0+rb*16+srow)*DM + kc);
      *(uint4*)&At[bi*512+l*8]=va;
      *(uint4*)&Bt[bi*512+l*8]=vb;
    }
    __syncthreads();
#pragma unroll
    for(int kh=0;kh<2;++kh){
      short8 af[4], bf[4];
#pragma unroll
      for(int i=0;i<4;++i) af[i]=*(short8*)&At[((wr4+i)*2+kh)*512+l*8];
#pragma unroll
      for(int j=0;j<4;++j) bf[j]=*(short8*)&Bt[((wc4+j)*2+kh)*512+l*8];
#pragma unroll
      for(int i=0;i<4;++i)
#pragma unroll
        for(int j=0;j<4;++j)
          acc[i][j]=__builtin_amdgcn_mfma_f32_16x16x32_bf16(af[i],bf[j],acc[i][j],0,0,0);
    }
  }
  gemm_epilogue(acc,mode,oflag,m0,n0,l,wr4,wc4,bias0,bias1,bias2,q,k,v,outv);
}

// ---------------- K2: MFMA xp_k + global max per bh --------------------------
__global__ __launch_bounds__(256) void k_xpk2(const u16* __restrict__ kb,
    const u16* __restrict__ pn, u32* __restrict__ kmax)
{
  __shared__ short Bt[32*512];
  __shared__ short At[8*512];
  __shared__ float red[256];
  const int t=threadIdx.x, l=t&63, w=t>>6;
  const int bh=blockIdx.y, nb0=blockIdx.x*256;
  for(int s=t;s<2048;s+=256){
    const int ub=s>>6, l2=s&63, mt=ub>>1, kh=ub&1;
    const int row=mt*16+(l2&15), kc=kh*32+(l2>>4)*8;
    *(uint4*)&Bt[ub*512+l2*8]=*(const uint4*)(pn + (size_t)row*DH + kc);
  }
  float vmax=-3.4e38f;
  for(int c=0;c<4;++c){
    const int n0=nb0+c*64;
    __syncthreads();
    for(int s=t;s<512;s+=256){
      const int ua=s>>6, l2=s&63, rb=ua>>1, kh=ua&1;
      const int n=n0+rb*16+(l2&15), kc=kh*32+(l2>>4)*8;
      *(uint4*)&At[ua*512+l2*8]=*(const uint4*)(kb + ((size_t)bh*NS+n)*DH + kc);
    }
    __syncthreads();
    const short8 af0=*(short8*)&At[(w*2+0)*512+l*8];
    const short8 af1=*(short8*)&At[(w*2+1)*512+l*8];
#pragma unroll
    for(int mt=0;mt<16;++mt){
      floatx4 a={};
      a=__builtin_amdgcn_mfma_f32_16x16x32_bf16(af0,*(short8*)&Bt[(mt*2+0)*512+l*8],a,0,0,0);
      a=__builtin_amdgcn_mfma_f32_16x16x32_bf16(af1,*(short8*)&Bt[(mt*2+1)*512+l*8],a,0,0,0);
      vmax=fmaxf(vmax,fmaxf(fmaxf(a[0],a[1]),fmaxf(a[2],a[3])));
    }
  }
  red[t]=vmax; __syncthreads();
  for(int s=128;s>0;s>>=1){ if(t<s) red[t]=fmaxf(red[t],red[t+s]); __syncthreads(); }
  if(t==0) atomicMax(kmax+bh, fkey(red[0]));
}

// ---------------- K3: MFMA fused kp -> ksum + ctx^T --------------------------
__global__ __launch_bounds__(256) void k_ctx2(const u16* __restrict__ kb,
    const u16* __restrict__ vT, const u16* __restrict__ pn,
    const float* __restrict__ dkbuf, const u32* __restrict__ kmax,
    float* __restrict__ ctxT, float* __restrict__ ksum)
{
  __shared__ short Bt[32*512];
  __shared__ u16   Ks[256*72];
  __shared__ short AtV[8*512];
  __shared__ float dg[64];
  const int t=threadIdx.x, l=t&63, w=t>>6;
  const int split=blockIdx.x, bh=blockIdx.y;
  for(int s=t;s<2048;s+=256){
    const int ub=s>>6, l2=s&63, mt=ub>>1, kh=ub&1;
    const int row=mt*16+(l2&15), kc=kh*32+(l2>>4)*8;
    *(uint4*)&Bt[ub*512+l2*8]=*(const uint4*)(pn + (size_t)row*DH + kc);
  }
  const float kM=funkey(kmax[bh]);
  float ksr=0.f;
  floatx4 acc2[4][4]={};
  for(int c=0;c<8;++c){
    const int n0=split*512+c*64;
    __syncthreads();
    for(int s=t;s<512;s+=256){
      const int ua=s>>6, l2=s&63, rb=ua>>1, kh=ua&1;
      const int n=n0+rb*16+(l2&15), kc=kh*32+(l2>>4)*8;
      *(uint4*)&AtV[ua*512+l2*8]=*(const uint4*)(kb + ((size_t)bh*NS+n)*DH + kc);
    }
    if(t<64) dg[t]=dkbuf[(size_t)bh*NS+n0+t];
    __syncthreads();
    short8 af[4][2];
#pragma unroll
    for(int rb=0;rb<4;++rb){
      af[rb][0]=*(short8*)&AtV[(rb*2+0)*512+l*8];
      af[rb][1]=*(short8*)&AtV[(rb*2+1)*512+l*8];
    }
    float dgl[16];
#pragma unroll
    for(int rb=0;rb<4;++rb)
#pragma unroll
      for(int r=0;r<4;++r) dgl[rb*4+r]=dg[rb*16+(l>>4)*4+r];
#pragma unroll
    for(int ml=0;ml<4;++ml){
      const int mt=w*4+ml;
      const short8 bf0=*(short8*)&Bt[(mt*2+0)*512+l*8];
      const short8 bf1=*(short8*)&Bt[(mt*2+1)*512+l*8];
      const int m=mt*16+(l&15);
#pragma unroll
      for(int rb=0;rb<4;++rb){
        floatx4 a={};
        a=__builtin_amdgcn_mfma_f32_16x16x32_bf16(af[rb][0],bf0,a,0,0,0);
        a=__builtin_amdgcn_mfma_f32_16x16x32_bf16(af[rb][1],bf1,a,0,0,0);
        const int nb=rb*16+(l>>4)*4;
        const float v0=RATIO*(__expf(a[0]-dgl[rb*4+0]-kM)+EPSV);
        const float v1=RATIO*(__expf(a[1]-dgl[rb*4+1]-kM)+EPSV);
        const float v2=RATIO*(__expf(a[2]-dgl[rb*4+2]-kM)+EPSV);
        const float v3=RATIO*(__expf(a[3]-dgl[rb*4+3]-kM)+EPSV);
        *(u32*)&Ks[m*72+nb]  =f2b(v0)|(f2b(v1)<<16);
        *(u32*)&Ks[m*72+nb+2]=f2b(v2)|(f2b(v3)<<16);
      }
    }
    __syncthreads();
    for(int s=t;s<512;s+=256){
      const int uv=s>>6, l2=s&63, dt=uv>>1, kh=uv&1;
      const int d=dt*16+(l2&15), nn=n0+kh*32+(l2>>4)*8;
      *(uint4*)&AtV[uv*512+l2*8]=*(const uint4*)(vT + ((size_t)bh*DH+d)*NS + nn);
    }
    {
      float s8=0.f;
#pragma unroll
      for(int j=0;j<8;++j){
        const uint4 kk=*(const uint4*)&Ks[t*72+j*8];
        s8+=b2f(kk.x&0xffffu)+b2f(kk.x>>16)+b2f(kk.y&0xffffu)+b2f(kk.y>>16)
           +b2f(kk.z&0xffffu)+b2f(kk.z>>16)+b2f(kk.w&0xffffu)+b2f(kk.w>>16);
      }
      ksr+=s8;
    }
    __syncthreads();
#pragma unroll
    for(int i=0;i<4;++i){
      const int row=(w*4+i)*16+(l&15);
      const short8 a0=*(short8*)&Ks[row*72 + 0*32+(l>>4)*8];
      const short8 a1=*(short8*)&Ks[row*72 + 1*32+(l>>4)*8];
#pragma unroll
      for(int dt=0;dt<4;++dt){
        acc2[i][dt]=__builtin_amdgcn_mfma_f32_16x16x32_bf16(a0,*(short8*)&AtV[(dt*2+0)*512+l*8],acc2[i][dt],0,0,0);
        acc2[i][dt]=__builtin_amdgcn_mfma_f32_16x16x32_bf16(a1,*(short8*)&AtV[(dt*2+1)*512+l*8],acc2[i][dt],0,0,0);
      }
    }
  }
#pragma unroll
  for(int i=0;i<4;++i){
#pragma unroll
    for(int dt=0;dt<4;++dt){
#pragma unroll
      for(int r=0;r<4;++r){
        const int m=(w*4+i)*16+(l>>4)*4+r;
        const int d=dt*16+(l&15);
        atomicAdd(&ctxT[((size_t)bh*DH+d)*MF+m], acc2[i][dt][r]);
      }
    }
  }
  atomicAdd(ksum+bh*MF+t, ksr);
}

// ---------------- K3b: split ctxT f32 -> hi/lo bf16, ecs=eps*colsum ----------
__global__ __launch_bounds__(256) void k_csplit(const float* __restrict__ ctxT,
    u16* __restrict__ chi, u16* __restrict__ clo, float* __restrict__ ecs)
{
  __shared__ float cred[256];
  const int bh=blockIdx.x, t=threadIdx.x;
  const int d=t>>2, part=t&3;
  const size_t base=((size_t)bh*DH+d)*MF + part*64;
  const float* src=ctxT + base;
  u16* ph=chi + base;
  u16* pl=clo + base;
  float cs=0.f;
  for(int m=0;m<64;m+=4){
    float4 v=*(const float4*)(src+m);
    float vv[4]={v.x,v.y,v.z,v.w};
    u32 h_[4], l_[4];
#pragma unroll
    for(int j=0;j<4;++j){
      cs+=vv[j];
      u32 hh=f2b(vv[j]);
      float rr=vv[j]-b2f(hh);
      h_[j]=hh; l_[j]=f2b(rr);
    }
    uint2 sh, sl;
    sh.x=h_[0]|(h_[1]<<16); sh.y=h_[2]|(h_[3]<<16);
    sl.x=l_[0]|(l_[1]<<16); sl.y=l_[2]|(l_[3]<<16);
    *(uint2*)(ph+m)=sh; *(uint2*)(pl+m)=sl;
  }
  cred[t]=cs; __syncthreads();
  if(part==0) ecs[bh*64+d]=EPSV*(cred[t]+cred[t+1]+cred[t+2]+cred[t+3]);
}

// ---------------- K4: MFMA fused qp + D_inv + attn ---------------------------
__global__ __launch_bounds__(256) void k_attn2(const u16* __restrict__ qb,
    const u16* __restrict__ pn, const float* __restrict__ dqbuf,
    const float* __restrict__ ksum, const u16* __restrict__ chi, const u16* __restrict__ clo,
    const float* __restrict__ ecs, u16* __restrict__ attn)
{
  __shared__ short At[8*512];
  __shared__ u16 Qf[32*512];
  __shared__ float ksums[256];
  __shared__ float dq_s[64];
  __shared__ float mxs[4][64];
  __shared__ float s1s[4][64];
  __shared__ float a_s[64], dinv_s[64], ec_s[64];
  __shared__ float red4[4];
  __shared__ float epkss;
  const int t=threadIdx.x, l=t&63, w=t>>6;
  const int bh=blockIdx.y, nb0=blockIdx.x*256;
  const int b_=bh/HN, h=bh%HN;
  {
    float kv=ksum[bh*MF+t];
    ksums[t]=kv;
    if(t<64) ec_s[t]=ecs[bh*64+t];
    float s=kv;
#pragma unroll
    for(int o=1;o<64;o<<=1) s+=__shfl_xor(s,o,64);
    if(l==0) red4[w]=s;
  }
  __syncthreads();
  if(t==0) epkss=EPSV*(red4[0]+red4[1]+red4[2]+red4[3]);
  short8 bhf[8], blf[8];
  {
    const int d=w*16+(l&15);
    const size_t base=((size_t)bh*DH+d)*MF;
#pragma unroll
    for(int kc=0;kc<8;++kc){
      const size_t off=base + kc*32+(l>>4)*8;
      bhf[kc]=*(const short8*)(chi+off);
      blf[kc]=*(const short8*)(clo+off);
    }
  }
  for(int c=0;c<4;++c){
    const int n0c=nb0+c*64;
    __syncthreads();
    for(int s=t;s<512;s+=256){
      const int ua=s>>6, l2=s&63, nt=ua>>1, kh=ua&1;
      const int n=n0c+nt*16+(l2&15), kc=kh*32+(l2>>4)*8;
      *(uint4*)&At[ua*512+l2*8]=*(const uint4*)(qb + ((size_t)bh*NS+n)*DH + kc);
    }
    if(t<64) dq_s[t]=dqbuf[(size_t)bh*NS+n0c+t];
    __syncthreads();
    float mxl[4]={-3.4e38f,-3.4e38f,-3.4e38f,-3.4e38f};
    float s1l[4]={0.f,0.f,0.f,0.f};
#pragma unroll
    for(int mt=0;mt<4;++mt){
      const int gm=w*4+mt;
      const u16* pr=pn + ((gm*16+(l&15))<<6) + (l>>4)*8;
      const short8 a0=*(const short8*)(pr);
      const short8 a1=*(const short8*)(pr+32);
      float k4[4];
#pragma unroll
      for(int r=0;r<4;++r) k4[r]=ksums[gm*16+(l>>4)*4+r];
      const int mbase=(gm&1)*16+(l>>4)*4;
      const int lane2=((mbase>>3)*16+(l&15))*8 + (mbase&7);
#pragma unroll
      for(int nt=0;nt<4;++nt){
        floatx4 xp={};
        xp=__builtin_amdgcn_mfma_f32_16x16x32_bf16(a0,*(short8*)&At[(nt*2+0)*512+l*8],xp,0,0,0);
        xp=__builtin_amdgcn_mfma_f32_16x16x32_bf16(a1,*(short8*)&At[(nt*2+1)*512+l*8],xp,0,0,0);
        const float dq=dq_s[nt*16+(l&15)];
        float ev[4];
#pragma unroll
        for(int r=0;r<4;++r){
          const float xv=xp[r];
          mxl[nt]=fmaxf(mxl[nt],xv);
          ev[r]=__expf(xv-dq);
          s1l[nt]+=ev[r]*k4[r];
        }
        u16* qp_=&Qf[(nt*8+(gm>>1))*512 + lane2];
        *(u32*)qp_    =f2b(ev[0])|(f2b(ev[1])<<16);
        *(u32*)(qp_+2)=f2b(ev[2])|(f2b(ev[3])<<16);
      }
    }
#pragma unroll
    for(int nt=0;nt<4;++nt){
      float m_=mxl[nt], s_=s1l[nt];
      m_=fmaxf(m_,__shfl_xor(m_,16,64)); s_+=__shfl_xor(s_,16,64);
      m_=fmaxf(m_,__shfl_xor(m_,32,64)); s_+=__shfl_xor(s_,32,64);
      if(l<16){ mxs[w][nt*16+l]=m_; s1s[w][nt*16+l]=s_; }
    }
    __syncthreads();
    if(t<64){
      float m_=fmaxf(fmaxf(mxs[0][t],mxs[1][t]),fmaxf(mxs[2][t],mxs[3][t]));
      float s_=s1s[0][t]+s1s[1][t]+s1s[2][t]+s1s[3][t];
      float a=__expf(-m_);
      a_s[t]=a;
      dinv_s[t]=1.0f/(a*s_+epkss);
    }
    __syncthreads();
    const int d=w*16+(l&15);
    const float ec=ec_s[d];
#pragma unroll
    for(int nt=0;nt<4;++nt){
      floatx4 y={};
#pragma unroll
      for(int kc=0;kc<8;++kc){
        const short8 e=*(short8*)&Qf[(nt*8+kc)*512+l*8];
        y=__builtin_amdgcn_mfma_f32_16x16x32_bf16(e,bhf[kc],y,0,0,0);
        y=__builtin_amdgcn_mfma_f32_16x16x32_bf16(e,blf[kc],y,0,0,0);
      }
#pragma unroll
      for(int r=0;r<4;++r){
        const int nl=nt*16+(l>>4)*4+r;
        const float val=(a_s[nl]*y[r]+ec)*dinv_s[nl];
        attn[((size_t)(b_*NS+n0c+nl))*DM + h*DH + d]=(u16)f2b(val);
      }
    }
  }
}

extern "C" void kernel_launch(void* const* d_in, const int* in_sizes, int n_in,
                              void* d_out, int out_size, void* d_ws, size_t ws_size,
                              hipStream_t stream)
{
  (void)in_sizes; (void)n_in; (void)out_size;
  const void* x =d_in[0];
  const void* Wq=d_in[1]; const void* bq=d_in[2];
  const void* Wk=d_in[3]; const void* bk=d_in[4];
  const void* Wv=d_in[5]; const void* bv=d_in[6];
  const void* Wo=d_in[7]; const void* bo=d_in[8];
  const void* proj=d_in[9];

  char* ws=(char*)d_ws;
  const size_t SZ=(size_t)BN*DM*2;               // 25,165,824 B
  const size_t AUXSZ=19030528;
  const bool big = ws_size >= 4*SZ + AUXSZ;      // ~119.7 MB
  u16*   qb  =(u16*)(ws);
  u16*   kb  =(u16*)(ws+SZ);
  u16*   vb  =(u16*)(ws+2*SZ);                   // v^T [bh][d][n]
  u16*   xb  =(u16*)(ws+3*SZ);                   // bf16 x (big path only)
  char*  aux = big ? (ws+4*SZ) : (ws+3*SZ);
  u16*   wb   =(u16*)(aux);                      // 3,538,944
  u16*   wob  =(u16*)(aux+3538944);              // -> 4,718,592
  float* ctxT =(float*)(aux+4718592);            // -> 11,010,048
  float* ksum =(float*)(aux+11010048);           // -> 11,108,352
  u32*   kmax =(u32*)(aux+11108352);             // -> 11,108,736
  int*   flag =(int*)(aux+11108736);             // -> 11,108,864
  float* dk   =(float*)(aux+11108864);           // -> 11,895,296
  float* dqq  =(float*)(aux+11895296);           // -> 12,681,728
  u16*   pn   =(u16*)(aux+12681728);             // -> 12,714,496
  u16*   chi  =(u16*)(aux+12714496);             // -> 15,860,224
  u16*   clo  =(u16*)(aux+15860224);             // -> 19,005,952
  float* ecs  =(float*)(aux+19005952);           // -> 19,030,528
  u16*   attnb = big ? xb : kb;                  // dead buffer reuse

  k_detect<<<1,64,0,stream>>>((const u16*)x, flag);
  hipMemsetAsync(ctxT, 0, 6291456+98304+384, stream);
  k_cvtw <<<1152, 256, 0, stream>>>(Wq,Wk,Wv,Wo,wb,wob,flag);
  k_cvtp <<<8, 256, 0, stream>>>(proj, pn, flag);
  if(big){
    k_cvtx <<<(BN*DM)/2048, 256, 0, stream>>>(x, xb, flag);
    k_gemm2<<<dim3(BN/128,2304/128), 256, 0, stream>>>(xb, wb, bq,bk,bv, qb,kb,vb, nullptr, flag, 0);
  }else{
    k_gemm_f<<<dim3(BN/128,2304/128), 256, 0, stream>>>(x, wb, bq,bk,bv, qb,kb,vb, nullptr, flag, 0);
  }
  k_diag <<<(BH*NS)/256, 256, 0, stream>>>(kb, dk);
  k_diag <<<(BH*NS)/256, 256, 0, stream>>>(qb, dqq);
  k_xpk2 <<<dim3(NS/256,BH), 256, 0, stream>>>(kb, pn, kmax);
  k_ctx2 <<<dim3(4,BH), 256, 0, stream>>>(kb, vb, pn, dk, kmax, ctxT, ksum);
  k_csplit<<<BH, 256, 0, stream>>>(ctxT, chi, clo, ecs);
  k_attn2<<<dim3(NS/256,BH), 256, 0, stream>>>(qb, pn, dqq, ksum, chi, clo, ecs, attnb);
  k_gemm2<<<dim3(BN/128,DM/128), 256, 0, stream>>>(attnb, wob, bo,bo,bo, nullptr,nullptr,nullptr, d_out, flag, 1);
}